// Round 9
// baseline (14191.104 us; speedup 1.0000x reference)
//
#include <hip/hip_runtime.h>
#include <math.h>

#define N_NODES 1024
#define HID 64
#define BATCH 16
#define TSTEPS 288
#define PWIN 24
#define PL 12
#define EMB 16
#define HOR 12
#define NPBLK 512u   // persistent grid size (2 blocks/CU guaranteed resident)

typedef __attribute__((ext_vector_type(4))) short short4_t;
typedef __attribute__((ext_vector_type(8))) short short8_t;
typedef _Float16 f16x8 __attribute__((ext_vector_type(8)));
typedef _Float16 f16x4 __attribute__((ext_vector_type(4)));
typedef float f32x4 __attribute__((ext_vector_type(4)));

__global__ __launch_bounds__(256) void fill_k(float* p, float v, int n) {
    int i = blockIdx.x*256 + threadIdx.x;
    if (i < n) p[i] = v;
}

// block per (ngrp, p): lane = n (coalesced stores), wave wid covers b = 4*wid..+3.
// Two-pass per b (amax pass, quantize pass) with 8-wide register chunks.
__global__ __launch_bounds__(256) void embedq4_k(
    const float* __restrict__ src, const float* __restrict__ vw,
    short* __restrict__ xqT, float* __restrict__ xsc2)
{
    int p = blockIdx.y;
    int n0 = blockIdx.x * 64;
    int t = threadIdx.x;
    int lane = t & 63, wid = t >> 6;
    __shared__ float sv[192][64];     // [b*12+tt][n]
    __shared__ float wvs[PL*HID];
    __shared__ float pe[64];
    for (int r = wid; r < 192; r += 4) {
        int b = r / 12, tt = r - b*12;
        sv[r][lane] = src[((size_t)b*TSTEPS + p*PL + tt)*N_NODES + n0 + lane];
    }
    for (int i = t; i < PL*HID; i += 256) wvs[i] = vw[i];
    if (t < 64) {
        float d = expf(-(float)(t & ~1) * (float)(9.210340371976184/64.0));
        float arg = (float)p * d;
        pe[t] = (t & 1) ? cosf(arg) : sinf(arg);
    }
    __syncthreads();
#pragma unroll 1
    for (int bb = 0; bb < 4; ++bb) {
        int b = wid*4 + bb;
        float svr[12];
#pragma unroll
        for (int tt = 0; tt < 12; ++tt) svr[tt] = sv[b*12 + tt][lane];
        float amax = 0.f;
#pragma unroll 1
        for (int h0 = 0; h0 < 64; h0 += 8) {
#pragma unroll
            for (int hh = 0; hh < 8; ++hh) {
                int h = h0 + hh;
                float d = pe[h];
#pragma unroll
                for (int tt = 0; tt < 12; ++tt) d += svr[tt] * wvs[tt*HID + h];
                amax = fmaxf(amax, fabsf(d));
            }
        }
        float inv = (amax > 0.f) ? 32767.f/amax : 0.f;
        short* xp = xqT + ((size_t)p << 20) + (size_t)b*64*1024 + n0 + lane;
#pragma unroll 1
        for (int h0 = 0; h0 < 64; h0 += 8) {
#pragma unroll
            for (int hh = 0; hh < 8; ++hh) {
                int h = h0 + hh;
                float d = pe[h];
#pragma unroll
                for (int tt = 0; tt < 12; ++tt) d += svr[tt] * wvs[tt*HID + h];
                xp[(size_t)h*1024] = (short)__float2int_rn(d*inv);
            }
        }
        xsc2[((p*16 + b) << 10) + n0 + lane] = (amax > 0.f) ? amax/32767.f : 0.f;
    }
}

// A[n][m] = softmax_m(relu(emb[n]·emb[m])), written as f16 hi/lo pair (compensated)
__global__ __launch_bounds__(256) void adj_k(const float* __restrict__ emb,
    _Float16* __restrict__ Ahi, _Float16* __restrict__ Alo)
{
    __shared__ float en[EMB];
    __shared__ float red[256];
    int n = blockIdx.x, t = threadIdx.x;
    if (t < EMB) en[t] = emb[n*EMB + t];
    __syncthreads();
    float v[4]; float mx = 0.f;
#pragma unroll
    for (int q = 0; q < 4; ++q) {
        int m = q*256 + t;
        float dot = 0.f;
#pragma unroll
        for (int e = 0; e < EMB; ++e) dot += en[e]*emb[m*EMB + e];
        v[q] = fmaxf(dot, 0.f);
        mx = fmaxf(mx, v[q]);
    }
    red[t] = mx; __syncthreads();
    for (int s2 = 128; s2 > 0; s2 >>= 1) {
        if (t < s2) red[t] = fmaxf(red[t], red[t + s2]);
        __syncthreads();
    }
    mx = red[0]; __syncthreads();
    float sum = 0.f;
#pragma unroll
    for (int q = 0; q < 4; ++q) { v[q] = expf(v[q] - mx); sum += v[q]; }
    red[t] = sum; __syncthreads();
    for (int s2 = 128; s2 > 0; s2 >>= 1) {
        if (t < s2) red[t] += red[t + s2];
        __syncthreads();
    }
    float inv = 1.f / red[0];
#pragma unroll
    for (int q = 0; q < 4; ++q) {
        float av = v[q]*inv;
        _Float16 hi = (_Float16)av;
        size_t idx = (size_t)n*N_NODES + q*256 + t;
        Ahi[idx] = hi;
        Alo[idx] = (_Float16)(av - (float)hi);
    }
}

// gwT[e][o][kc] <- gwl[e][kc][o]
template<int OUT>
__global__ __launch_bounds__(256) void wtrans_k(
    const float* __restrict__ gwl, float* __restrict__ gwT)
{
    int idx = blockIdx.x*256 + threadIdx.x;
    int kc = idx & 255;
    int rest = idx >> 8;
    int o = rest % OUT;
    int e = rest / OUT;
    gwT[idx] = gwl[((size_t)e*256 + kc)*OUT + o];
}

// W[n][o][kc] = sum_e emb[n][e]*gwT[e][o][kc], i16 with per-(n,o) row scale.
template<int OUT>
__global__ __launch_bounds__(256) void wnodeq2_k(
    const float* __restrict__ emb, const float* __restrict__ gwT,
    short* __restrict__ WQ, float* __restrict__ wsc)
{
    int t = threadIdx.x;
    int n0 = blockIdx.x * 4;
    int oh = blockIdx.y;
    int lane = t & 63, w = t >> 6;
    __shared__ float se[4][EMB];
    if (t < 4*EMB) se[t >> 4][t & 15] = emb[(n0 + (t >> 4))*EMB + (t & 15)];
    __syncthreads();
    for (int o = oh*(OUT/4) + w; o < (oh+1)*(OUT/4); o += 4) {
        const float* gp = gwT + (size_t)o*256 + lane*4;
        float4 s[4];
#pragma unroll
        for (int ng = 0; ng < 4; ++ng) s[ng] = make_float4(0.f, 0.f, 0.f, 0.f);
#pragma unroll
        for (int e = 0; e < EMB; ++e) {
            float4 g = *(const float4*)(gp + (size_t)e*(OUT*256));
#pragma unroll
            for (int ng = 0; ng < 4; ++ng) {
                float c = se[ng][e];
                s[ng].x += c*g.x; s[ng].y += c*g.y; s[ng].z += c*g.z; s[ng].w += c*g.w;
            }
        }
#pragma unroll
        for (int ng = 0; ng < 4; ++ng) {
            float amax = fmaxf(fmaxf(fabsf(s[ng].x), fabsf(s[ng].y)),
                               fmaxf(fabsf(s[ng].z), fabsf(s[ng].w)));
#pragma unroll
            for (int d = 32; d > 0; d >>= 1) amax = fmaxf(amax, __shfl_xor(amax, d));
            float inv = (amax > 0.f) ? 32767.f/amax : 0.f;
            short4_t q;
            q.x = (short)__float2int_rn(s[ng].x*inv);
            q.y = (short)__float2int_rn(s[ng].y*inv);
            q.z = (short)__float2int_rn(s[ng].z*inv);
            q.w = (short)__float2int_rn(s[ng].w*inv);
            *(short4_t*)(WQ + ((size_t)(n0+ng)*OUT + o)*256 + lane*4) = q;
            if (lane == 0) wsc[(n0+ng)*OUT + o] = (amax > 0.f) ? amax/32767.f : 0.f;
        }
    }
}

__global__ __launch_bounds__(256) void bias_k(const float* __restrict__ emb,
                        const float* __restrict__ gbl, float* __restrict__ bn, int OUT)
{
    int idx = blockIdx.x*256 + threadIdx.x;
    if (idx >= N_NODES*OUT) return;
    int n = idx / OUT, o = idx % OUT;
    float s = 0.f;
#pragma unroll
    for (int e = 0; e < EMB; ++e) s += emb[n*EMB + e]*gbl[e*OUT + o];
    bn[idx] = s;
}

// ---- persistent-scan argument block ----
struct PArgs {
    const _Float16* Ahi; const _Float16* Alo;
    short* xqT;            // [p][j][n] i16
    const float* xsc;      // [p][b][n] scales
    const short* WgQ; const float* swg; const float* bgn;
    const short* WuQ; const float* swu; const float* bun;
    float* hbuf;           // h rows [n][j]
    float* hT;             // h cols [j][n]
    float* zrb;            // [n][b][128]
    float* zhT;            // (z*h)^T [j][n]
    float* pAh;            // split-K pair
    float* pAx;            // DOUBLE split-K pair (cur/nxt)
    float* pAzh;           // split-K pair
    int wx;                // write next-layer x
};

// Hand-rolled grid barrier (regular launch; all NPBLK blocks co-resident).
// Agent-scope fences handle cross-XCD L2 non-coherence (§6 G16).
__device__ __forceinline__ void gbar(unsigned* cnt, unsigned* gen)
{
    __syncthreads();
    if (threadIdx.x == 0) {
        __threadfence();   // release: write back this XCD's L2
        unsigned g = __hip_atomic_load(gen, __ATOMIC_ACQUIRE, __HIP_MEMORY_SCOPE_AGENT);
        unsigned a = __hip_atomic_fetch_add(cnt, 1u, __ATOMIC_ACQ_REL, __HIP_MEMORY_SCOPE_AGENT);
        if (a == NPBLK - 1u) {
            __hip_atomic_store(cnt, 0u, __ATOMIC_RELAXED, __HIP_MEMORY_SCOPE_AGENT);
            __hip_atomic_store(gen, g + 1u, __ATOMIC_RELEASE, __HIP_MEMORY_SCOPE_AGENT);
        } else {
            unsigned cur;
            do {
                __builtin_amdgcn_s_sleep(2);
                cur = __hip_atomic_load(gen, __ATOMIC_RELAXED, __HIP_MEMORY_SCOPE_AGENT);
            } while (cur == g);
        }
        __threadfence();   // acquire: invalidate stale L2 lines
    }
    __syncthreads();
}

// One 64x64 tile, K-half ks, of C = A@B (f32-emulated f16 MFMA).
// mode 0: B = BTf (f32, transposed [j][m]);  mode 1: B = xqTp i16 * xscp[b][m].
__device__ void gemm_tile(const _Float16* __restrict__ Ahi, const _Float16* __restrict__ Alo,
    const float* __restrict__ BTf, const short* __restrict__ xqTp,
    const float* __restrict__ xscp, int mode, int tile, int ks,
    float* __restrict__ out, _Float16* ls)
{
    _Float16* Ash = ls;
    _Float16* Asl = ls + 64*72;
    _Float16* Bsh = ls + 2*64*72;
    _Float16* Bsl = ls + 3*64*72;
    int t = threadIdx.x;
    int l = t & 63, w = t >> 6;
    int wr = w >> 1, wc = w & 1;
    int r0 = (tile >> 4)*64, c0 = (tile & 15)*64;
    int kbase = ks << 9;
    f32x4 acc[2][2];
#pragma unroll
    for (int i = 0; i < 2; ++i)
#pragma unroll
        for (int j = 0; j < 2; ++j) acc[i][j] = (f32x4){0.f,0.f,0.f,0.f};
    int arow = wr*32 + (l & 15);
    int brow = wc*32 + (l & 15);
    int koff = (l >> 4)*8;
    const float* sbase = (mode == 1) ? xscp + ((c0 >> 6) << 10) : nullptr;
    for (int k0 = kbase; k0 < kbase + 512; k0 += 64) {
        __syncthreads();
#pragma unroll
        for (int c = 0; c < 2; ++c) {
            int id = t + 256*c;
            int row = id >> 3, k8 = id & 7;
            *(f16x8*)(&Ash[row*72 + k8*8]) =
                *(const f16x8*)(&Ahi[(size_t)(r0+row)*1024 + k0 + k8*8]);
            *(f16x8*)(&Asl[row*72 + k8*8]) =
                *(const f16x8*)(&Alo[(size_t)(r0+row)*1024 + k0 + k8*8]);
        }
        if (mode == 1) {
#pragma unroll
            for (int c = 0; c < 2; ++c) {
                int id = t + 256*c;
                int row = id >> 3, k8 = id & 7;
                short8_t q8 = *(const short8_t*)(xqTp + (size_t)(c0+row)*1024 + k0 + k8*8);
                float4 s0 = *(const float4*)(sbase + k0 + k8*8);
                float4 s1 = *(const float4*)(sbase + k0 + k8*8 + 4);
                float vv[8];
                vv[0] = (float)q8[0]*s0.x; vv[1] = (float)q8[1]*s0.y;
                vv[2] = (float)q8[2]*s0.z; vv[3] = (float)q8[3]*s0.w;
                vv[4] = (float)q8[4]*s1.x; vv[5] = (float)q8[5]*s1.y;
                vv[6] = (float)q8[6]*s1.z; vv[7] = (float)q8[7]*s1.w;
                f16x8 hi, lo;
#pragma unroll
                for (int i = 0; i < 8; ++i) {
                    _Float16 h = (_Float16)vv[i];
                    hi[i] = h;
                    lo[i] = (_Float16)(vv[i] - (float)h);
                }
                *(f16x8*)(&Bsh[row*72 + k8*8]) = hi;
                *(f16x8*)(&Bsl[row*72 + k8*8]) = lo;
            }
        } else {
#pragma unroll
            for (int c = 0; c < 4; ++c) {
                int id = t + 256*c;
                int row = id >> 4, kq = id & 15;
                float4 v = *(const float4*)(&BTf[(size_t)(c0+row)*1024 + k0 + kq*4]);
                float vv[4] = {v.x, v.y, v.z, v.w};
                f16x4 hi, lo;
#pragma unroll
                for (int i = 0; i < 4; ++i) {
                    _Float16 h = (_Float16)vv[i];
                    hi[i] = h;
                    lo[i] = (_Float16)(vv[i] - (float)h);
                }
                *(f16x4*)(&Bsh[row*72 + kq*4]) = hi;
                *(f16x4*)(&Bsl[row*72 + kq*4]) = lo;
            }
        }
        __syncthreads();
#pragma unroll
        for (int kk = 0; kk < 2; ++kk) {
            int ko = kk*32 + koff;
            f16x8 ah0 = *(const f16x8*)(&Ash[(size_t)arow*72 + ko]);
            f16x8 ah1 = *(const f16x8*)(&Ash[(size_t)(arow+16)*72 + ko]);
            f16x8 al0 = *(const f16x8*)(&Asl[(size_t)arow*72 + ko]);
            f16x8 al1 = *(const f16x8*)(&Asl[(size_t)(arow+16)*72 + ko]);
            f16x8 bh0 = *(const f16x8*)(&Bsh[(size_t)brow*72 + ko]);
            f16x8 bh1 = *(const f16x8*)(&Bsh[(size_t)(brow+16)*72 + ko]);
            f16x8 bl0 = *(const f16x8*)(&Bsl[(size_t)brow*72 + ko]);
            f16x8 bl1 = *(const f16x8*)(&Bsl[(size_t)(brow+16)*72 + ko]);
            acc[0][0] = __builtin_amdgcn_mfma_f32_16x16x32_f16(al0, bh0, acc[0][0], 0, 0, 0);
            acc[0][0] = __builtin_amdgcn_mfma_f32_16x16x32_f16(ah0, bl0, acc[0][0], 0, 0, 0);
            acc[0][0] = __builtin_amdgcn_mfma_f32_16x16x32_f16(ah0, bh0, acc[0][0], 0, 0, 0);
            acc[0][1] = __builtin_amdgcn_mfma_f32_16x16x32_f16(al0, bh1, acc[0][1], 0, 0, 0);
            acc[0][1] = __builtin_amdgcn_mfma_f32_16x16x32_f16(ah0, bl1, acc[0][1], 0, 0, 0);
            acc[0][1] = __builtin_amdgcn_mfma_f32_16x16x32_f16(ah0, bh1, acc[0][1], 0, 0, 0);
            acc[1][0] = __builtin_amdgcn_mfma_f32_16x16x32_f16(al1, bh0, acc[1][0], 0, 0, 0);
            acc[1][0] = __builtin_amdgcn_mfma_f32_16x16x32_f16(ah1, bl0, acc[1][0], 0, 0, 0);
            acc[1][0] = __builtin_amdgcn_mfma_f32_16x16x32_f16(ah1, bh0, acc[1][0], 0, 0, 0);
            acc[1][1] = __builtin_amdgcn_mfma_f32_16x16x32_f16(al1, bh1, acc[1][1], 0, 0, 0);
            acc[1][1] = __builtin_amdgcn_mfma_f32_16x16x32_f16(ah1, bl1, acc[1][1], 0, 0, 0);
            acc[1][1] = __builtin_amdgcn_mfma_f32_16x16x32_f16(ah1, bh1, acc[1][1], 0, 0, 0);
        }
    }
#pragma unroll
    for (int fr = 0; fr < 2; ++fr)
#pragma unroll
        for (int fc = 0; fc < 2; ++fc) {
            int orow = r0 + wr*32 + fr*16 + ((l >> 4) << 2);
            int ocol = c0 + wc*32 + fc*16 + (l & 15);
#pragma unroll
            for (int i = 0; i < 4; ++i)
                out[(size_t)(orow+i)*1024 + ocol] = acc[fr][fc][i];
        }
}

__device__ void gate_phase(const PArgs& a, int n, bool first,
    const short* __restrict__ xq_ps, const float* __restrict__ xsc_ps,
    const float* __restrict__ pAxC, _Float16* ls)
{
    float* inp = (float*)ls;
    int t = threadIdx.x;
    size_t nb = (size_t)n*1024;
    __syncthreads();
    for (int i = t; i < 1024; i += 256) {
        int b = i >> 6, c = i & 63;
        float sx = xsc_ps[(b << 10) + n];
        inp[b*256 + c]       = (float)xq_ps[(size_t)i*1024 + n] * sx;
        inp[b*256 + 64 + c]  = first ? 0.f : a.hbuf[nb + i];
        inp[b*256 + 128 + c] = pAxC[nb + i] + pAxC[nb + i + 1048576];
        inp[b*256 + 192 + c] = first ? 0.f : (a.pAh[nb + i] + a.pAh[nb + i + 1048576]);
    }
    __syncthreads();
    int o = t & 127, g = t >> 7;
    const short* wp = a.WgQ + ((size_t)n*128 + o)*256;
    float ws = a.swg[n*128 + o];
    float bias = a.bgn[n*128 + o];
    float acc[8];
#pragma unroll
    for (int u = 0; u < 8; ++u) acc[u] = 0.f;
    for (int k0 = 0; k0 < 256; k0 += 4) {
        short4_t w4 = *(const short4_t*)(wp + k0);
        float w0 = (float)w4.x, w1 = (float)w4.y, w2 = (float)w4.z, w3 = (float)w4.w;
#pragma unroll
        for (int u = 0; u < 8; ++u) {
            float4 iv = *(const float4*)(&inp[(g*8 + u)*256 + k0]);
            acc[u] += w0*iv.x + w1*iv.y + w2*iv.z + w3*iv.w;
        }
    }
#pragma unroll
    for (int u = 0; u < 8; ++u) {
        int b = g*8 + u;
        float pre = acc[u]*ws + bias;
        float val = 1.f/(1.f + expf(-pre));
        a.zrb[((size_t)n*16 + b)*128 + o] = val;
        if (!first && o < 64)
            a.zhT[(size_t)(b*64 + o)*1024 + n] = val * inp[b*256 + 64 + o];
    }
}

__device__ void upd_phase(const PArgs& a, int n, bool first,
    short* __restrict__ xq_ps, const float* __restrict__ xsc_ps,
    const float* __restrict__ pAxC, _Float16* ls)
{
    float* inp = (float*)ls;
    int t = threadIdx.x;
    size_t nb = (size_t)n*1024;
    __syncthreads();
    for (int i = t; i < 1024; i += 256) {
        int b = i >> 6, c = i & 63;
        float sx = xsc_ps[(b << 10) + n];
        float hv = first ? 0.f : a.hbuf[nb + i];
        float zv = a.zrb[((size_t)n*16 + b)*128 + c];
        inp[b*256 + c]       = (float)xq_ps[(size_t)i*1024 + n] * sx;
        inp[b*256 + 64 + c]  = zv * hv;
        inp[b*256 + 128 + c] = pAxC[nb + i] + pAxC[nb + i + 1048576];
        inp[b*256 + 192 + c] = first ? 0.f : (a.pAzh[nb + i] + a.pAzh[nb + i + 1048576]);
    }
    __syncthreads();
    int o = t & 63, g = t >> 6;
    const short* wp = a.WuQ + ((size_t)n*64 + o)*256;
    float ws = a.swu[n*64 + o];
    float bias = a.bun[n*64 + o];
    float acc[4];
#pragma unroll
    for (int u = 0; u < 4; ++u) acc[u] = 0.f;
    for (int k0 = 0; k0 < 256; k0 += 4) {
        short4_t w4 = *(const short4_t*)(wp + k0);
        float w0 = (float)w4.x, w1 = (float)w4.y, w2 = (float)w4.z, w3 = (float)w4.w;
#pragma unroll
        for (int u = 0; u < 4; ++u) {
            float4 iv = *(const float4*)(&inp[(g*4 + u)*256 + k0]);
            acc[u] += w0*iv.x + w1*iv.y + w2*iv.z + w3*iv.w;
        }
    }
#pragma unroll
    for (int u = 0; u < 4; ++u) {
        int b = g*4 + u;
        float r = a.zrb[((size_t)n*16 + b)*128 + 64 + o];
        float hold = first ? 0.f : a.hbuf[nb + b*64 + o];
        float hc = tanhf(acc[u]*ws + bias);
        float hn = r*hold + (1.f - r)*hc;
        a.hbuf[nb + b*64 + o] = hn;
        a.hT[(size_t)(b*64 + o)*1024 + n] = hn;
        if (a.wx) xq_ps[(size_t)(b*64 + o)*1024 + n] = (short)__float2int_rn(hn*32767.f);
    }
}

// Whole 24-step scan for one layer. NPBLK blocks (2/CU), regular launch +
// hand-rolled grid barrier. Per step: P1 A@h | P2 gate | P3 A@zh + A@x_{t+1} | P4 upd.
__global__ __launch_bounds__(256, 2) void persist_k(PArgs a, unsigned* bcnt, unsigned* bgen)
{
    __shared__ __align__(16) _Float16 ls[4*64*72];    // 36.9 KB, phase-shared
    int bid = blockIdx.x;      // 0..511

    // pre-phase: A@x_0 -> pAx buffer 0
    {
        int ks = bid & 1, tile = bid >> 1;
        gemm_tile(a.Ahi, a.Alo, nullptr, a.xqT, a.xsc, 1, tile, ks,
                  a.pAx + ((size_t)ks << 20), ls);
    }
    gbar(bcnt, bgen);

    for (int ps = 0; ps < PWIN; ++ps) {
        int cur = ps & 1;
        short* xq_ps = a.xqT + ((size_t)ps << 20);
        const float* xsc_ps = a.xsc + (size_t)ps*16384;
        float* pAxC = a.pAx + (size_t)cur*2097152;
        float* pAxN = a.pAx + (size_t)(cur ^ 1)*2097152;
        bool first = (ps == 0);

        // P1: A@h (skip at ps==0; h==0)
        if (!first) {
            int ks = bid & 1, tile = bid >> 1;
            gemm_tile(a.Ahi, a.Alo, a.hT, nullptr, nullptr, 0, tile, ks,
                      a.pAh + ((size_t)ks << 20), ls);
        }
        gbar(bcnt, bgen);

        // P2: gate (2 nodes per block, XCD-swizzled)
        for (int it = 0; it < 2; ++it) {
            int idx = bid + it*512;
            int n = ((idx & 7) << 7) | (idx >> 3);
            gate_phase(a, n, first, xq_ps, xsc_ps, pAxC, ls);
        }
        gbar(bcnt, bgen);

        // P3: A@(z*h)  and  A@x_{ps+1} (prefetch for next step)
        for (int it = 0; it < 2; ++it) {
            int job = bid + it*512;
            if (job < 512) {
                if (!first) {
                    int ks = job & 1, tile = job >> 1;
                    gemm_tile(a.Ahi, a.Alo, a.zhT, nullptr, nullptr, 0, tile, ks,
                              a.pAzh + ((size_t)ks << 20), ls);
                }
            } else {
                if (ps + 1 < PWIN) {
                    int j2 = job - 512, ks = j2 & 1, tile = j2 >> 1;
                    gemm_tile(a.Ahi, a.Alo, nullptr, a.xqT + ((size_t)(ps+1) << 20),
                              a.xsc + (size_t)(ps+1)*16384, 1, tile, ks,
                              pAxN + ((size_t)ks << 20), ls);
                }
            }
        }
        gbar(bcnt, bgen);

        // P4: upd
        for (int it = 0; it < 2; ++it) {
            int idx = bid + it*512;
            int n = ((idx & 7) << 7) | (idx >> 3);
            upd_phase(a, n, first, xq_ps, xsc_ps, pAxC, ls);
        }
        gbar(bcnt, bgen);
    }
}

// out[b][o][n] = h[n][b][:]·ecw[o][:] + ecb[o]
__global__ __launch_bounds__(256) void endconv_k(
    const float* __restrict__ hst, const float* __restrict__ ecw,
    const float* __restrict__ ecb, float* __restrict__ out)
{
    int idx = blockIdx.x*256 + threadIdx.x;
    int n = idx & 1023;
    int o = (idx >> 10) % HOR;
    int b = idx / (HOR*1024);
    float s = ecb[o];
#pragma unroll
    for (int hh = 0; hh < 64; ++hh)
        s += hst[((size_t)n*16 + b)*64 + hh] * ecw[o*64 + hh];
    out[idx] = s;
}

extern "C" void kernel_launch(void* const* d_in, const int* in_sizes, int n_in,
                              void* d_out, int out_size, void* d_ws, size_t ws_size,
                              hipStream_t stream)
{
    const float* source = (const float*)d_in[0];
    const float* emb    = (const float*)d_in[2];
    const float* vw     = (const float*)d_in[3];
    const float* gate_w = (const float*)d_in[4];
    const float* gate_b = (const float*)d_in[5];
    const float* upd_w  = (const float*)d_in[6];
    const float* upd_b  = (const float*)d_in[7];
    const float* ecw    = (const float*)d_in[8];
    const float* ecb    = (const float*)d_in[9];
    float* out = (float*)d_out;

    // ---- workspace carve: ~205 MB ----
    char* p = (char*)d_ws;
    _Float16* Ahi = (_Float16*)p; p += (size_t)1048576*2;    //   2.0 MB
    _Float16* Alo = (_Float16*)p; p += (size_t)1048576*2;    //   2.0 MB
    short* WgQ  = (short*)p;  p += (size_t)33554432*2;       //  64.0 MB
    short* WuQ  = (short*)p;  p += (size_t)16777216*2;       //  32.0 MB
    float* swg  = (float*)p;  p += (size_t)131072*4;         //   0.5 MB
    float* swu  = (float*)p;  p += (size_t)65536*4;          //   0.25 MB
    float* bgn  = (float*)p;  p += (size_t)131072*4;         //   0.5 MB
    float* bun  = (float*)p;  p += (size_t)65536*4;          //   0.25 MB
    short* xqT  = (short*)p;  p += (size_t)25165824*2;       //  48.0 MB  [p][j][n] i16
    float* xscA = (float*)p;  p += (size_t)393216*4;         //   1.5 MB
    float* xscB = (float*)p;  p += (size_t)393216*4;         //   1.5 MB
    float* hbuf = (float*)p;  p += (size_t)1048576*4;        //   4.0 MB
    float* hT   = (float*)p;  p += (size_t)1048576*4;        //   4.0 MB
    float* zrb  = (float*)p;  p += (size_t)2097152*4;        //   8.0 MB
    float* zhT  = (float*)p;  p += (size_t)1048576*4;        //   4.0 MB
    float* pAh  = (float*)p;  p += (size_t)2097152*4;        //   8.0 MB  split-K pair
    float* pAx  = (float*)p;  p += (size_t)4194304*4;        //  16.0 MB  2 x split-K pair
    float* pAzh = (float*)p;  p += (size_t)2097152*4;        //   8.0 MB  split-K pair
    unsigned* barb = (unsigned*)p; p += 256;                  //  barrier state
    float* gwT  = pAzh;   // 2 MB scratch, aliases pAzh (dead during layer setup)

    fill_k<<<1, 256, 0, stream>>>((float*)barb, 0.f, 2);     // cnt=0, gen=0
    embedq4_k<<<dim3(16,24), 256, 0, stream>>>(source, vw, xqT, xscA);
    adj_k<<<1024, 256, 0, stream>>>(emb, Ahi, Alo);
    fill_k<<<1536, 256, 0, stream>>>(xscB, 1.f/32767.f, 393216);

    for (int l = 0; l < 2; ++l) {
        const float* xsc2 = (l == 0) ? xscA : xscB;
        wtrans_k<128><<<2048, 256, 0, stream>>>(gate_w + (size_t)l*524288, gwT);
        wnodeq2_k<128><<<dim3(256,4), 256, 0, stream>>>(emb, gwT, WgQ, swg);
        wtrans_k<64><<<1024, 256, 0, stream>>>(upd_w + (size_t)l*262144, gwT);
        wnodeq2_k<64><<<dim3(256,4), 256, 0, stream>>>(emb, gwT, WuQ, swu);
        bias_k<<<512, 256, 0, stream>>>(emb, gate_b + l*2048, bgn, 128);
        bias_k<<<256, 256, 0, stream>>>(emb, upd_b + l*1024, bun, 64);

        PArgs pa;
        pa.Ahi = Ahi; pa.Alo = Alo;
        pa.xqT = xqT; pa.xsc = xsc2;
        pa.WgQ = WgQ; pa.swg = swg; pa.bgn = bgn;
        pa.WuQ = WuQ; pa.swu = swu; pa.bun = bun;
        pa.hbuf = hbuf; pa.hT = hT; pa.zrb = zrb; pa.zhT = zhT;
        pa.pAh = pAh; pa.pAx = pAx; pa.pAzh = pAzh;
        pa.wx = (l == 0) ? 1 : 0;
        persist_k<<<NPBLK, 256, 0, stream>>>(pa, barb, barb + 64);
    }
    endconv_k<<<768, 256, 0, stream>>>(hbuf, ecw, ecb, out);
}

// Round 10
// 6726.131 us; speedup vs baseline: 2.1098x; 2.1098x over previous
//
#include <hip/hip_runtime.h>
#include <math.h>

#define N_NODES 1024
#define HID 64
#define BATCH 16
#define TSTEPS 288
#define PWIN 24
#define PL 12
#define EMB 16
#define HOR 12

typedef __attribute__((ext_vector_type(4))) short short4_t;
typedef __attribute__((ext_vector_type(8))) short short8_t;
typedef _Float16 f16x8 __attribute__((ext_vector_type(8)));
typedef _Float16 f16x4 __attribute__((ext_vector_type(4)));
typedef float f32x4 __attribute__((ext_vector_type(4)));

__global__ __launch_bounds__(256) void fill_k(float* p, float v, int n) {
    int i = blockIdx.x*256 + threadIdx.x;
    if (i < n) p[i] = v;
}

// block per (ngrp, p): lane = n (coalesced stores), wave wid covers b = 4*wid..+3.
// Two-pass per b (amax pass, quantize pass) with 8-wide register chunks.
__global__ __launch_bounds__(256) void embedq4_k(
    const float* __restrict__ src, const float* __restrict__ vw,
    short* __restrict__ xqT, float* __restrict__ xsc2)
{
    int p = blockIdx.y;
    int n0 = blockIdx.x * 64;
    int t = threadIdx.x;
    int lane = t & 63, wid = t >> 6;
    __shared__ float sv[192][64];     // [b*12+tt][n]
    __shared__ float wvs[PL*HID];
    __shared__ float pe[64];
    for (int r = wid; r < 192; r += 4) {
        int b = r / 12, tt = r - b*12;
        sv[r][lane] = src[((size_t)b*TSTEPS + p*PL + tt)*N_NODES + n0 + lane];
    }
    for (int i = t; i < PL*HID; i += 256) wvs[i] = vw[i];
    if (t < 64) {
        float d = expf(-(float)(t & ~1) * (float)(9.210340371976184/64.0));
        float arg = (float)p * d;
        pe[t] = (t & 1) ? cosf(arg) : sinf(arg);
    }
    __syncthreads();
#pragma unroll 1
    for (int bb = 0; bb < 4; ++bb) {
        int b = wid*4 + bb;
        float svr[12];
#pragma unroll
        for (int tt = 0; tt < 12; ++tt) svr[tt] = sv[b*12 + tt][lane];
        float amax = 0.f;
#pragma unroll 1
        for (int h0 = 0; h0 < 64; h0 += 8) {
#pragma unroll
            for (int hh = 0; hh < 8; ++hh) {
                int h = h0 + hh;
                float d = pe[h];
#pragma unroll
                for (int tt = 0; tt < 12; ++tt) d += svr[tt] * wvs[tt*HID + h];
                amax = fmaxf(amax, fabsf(d));
            }
        }
        float inv = (amax > 0.f) ? 32767.f/amax : 0.f;
        short* xp = xqT + ((size_t)p << 20) + (size_t)b*64*1024 + n0 + lane;
#pragma unroll 1
        for (int h0 = 0; h0 < 64; h0 += 8) {
#pragma unroll
            for (int hh = 0; hh < 8; ++hh) {
                int h = h0 + hh;
                float d = pe[h];
#pragma unroll
                for (int tt = 0; tt < 12; ++tt) d += svr[tt] * wvs[tt*HID + h];
                xp[(size_t)h*1024] = (short)__float2int_rn(d*inv);
            }
        }
        xsc2[((p*16 + b) << 10) + n0 + lane] = (amax > 0.f) ? amax/32767.f : 0.f;
    }
}

// A[n][m] = softmax_m(relu(emb[n]·emb[m])), written as f16 hi/lo pair (compensated)
__global__ __launch_bounds__(256) void adj_k(const float* __restrict__ emb,
    _Float16* __restrict__ Ahi, _Float16* __restrict__ Alo)
{
    __shared__ float en[EMB];
    __shared__ float red[256];
    int n = blockIdx.x, t = threadIdx.x;
    if (t < EMB) en[t] = emb[n*EMB + t];
    __syncthreads();
    float v[4]; float mx = 0.f;
#pragma unroll
    for (int q = 0; q < 4; ++q) {
        int m = q*256 + t;
        float dot = 0.f;
#pragma unroll
        for (int e = 0; e < EMB; ++e) dot += en[e]*emb[m*EMB + e];
        v[q] = fmaxf(dot, 0.f);
        mx = fmaxf(mx, v[q]);
    }
    red[t] = mx; __syncthreads();
    for (int s2 = 128; s2 > 0; s2 >>= 1) {
        if (t < s2) red[t] = fmaxf(red[t], red[t + s2]);
        __syncthreads();
    }
    mx = red[0]; __syncthreads();
    float sum = 0.f;
#pragma unroll
    for (int q = 0; q < 4; ++q) { v[q] = expf(v[q] - mx); sum += v[q]; }
    red[t] = sum; __syncthreads();
    for (int s2 = 128; s2 > 0; s2 >>= 1) {
        if (t < s2) red[t] += red[t + s2];
        __syncthreads();
    }
    float inv = 1.f / red[0];
#pragma unroll
    for (int q = 0; q < 4; ++q) {
        float av = v[q]*inv;
        _Float16 hi = (_Float16)av;
        size_t idx = (size_t)n*N_NODES + q*256 + t;
        Ahi[idx] = hi;
        Alo[idx] = (_Float16)(av - (float)hi);
    }
}

// gwT[e][o][kc] <- gwl[e][kc][o]
template<int OUT>
__global__ __launch_bounds__(256) void wtrans_k(
    const float* __restrict__ gwl, float* __restrict__ gwT)
{
    int idx = blockIdx.x*256 + threadIdx.x;
    int kc = idx & 255;
    int rest = idx >> 8;
    int o = rest % OUT;
    int e = rest / OUT;
    gwT[idx] = gwl[((size_t)e*256 + kc)*OUT + o];
}

// W[n][o][kc] = sum_e emb[n][e]*gwT[e][o][kc], i16 with per-(n,o) row scale.
template<int OUT>
__global__ __launch_bounds__(256) void wnodeq2_k(
    const float* __restrict__ emb, const float* __restrict__ gwT,
    short* __restrict__ WQ, float* __restrict__ wsc)
{
    int t = threadIdx.x;
    int n0 = blockIdx.x * 4;
    int oh = blockIdx.y;
    int lane = t & 63, w = t >> 6;
    __shared__ float se[4][EMB];
    if (t < 4*EMB) se[t >> 4][t & 15] = emb[(n0 + (t >> 4))*EMB + (t & 15)];
    __syncthreads();
    for (int o = oh*(OUT/4) + w; o < (oh+1)*(OUT/4); o += 4) {
        const float* gp = gwT + (size_t)o*256 + lane*4;
        float4 s[4];
#pragma unroll
        for (int ng = 0; ng < 4; ++ng) s[ng] = make_float4(0.f, 0.f, 0.f, 0.f);
#pragma unroll
        for (int e = 0; e < EMB; ++e) {
            float4 g = *(const float4*)(gp + (size_t)e*(OUT*256));
#pragma unroll
            for (int ng = 0; ng < 4; ++ng) {
                float c = se[ng][e];
                s[ng].x += c*g.x; s[ng].y += c*g.y; s[ng].z += c*g.z; s[ng].w += c*g.w;
            }
        }
#pragma unroll
        for (int ng = 0; ng < 4; ++ng) {
            float amax = fmaxf(fmaxf(fabsf(s[ng].x), fabsf(s[ng].y)),
                               fmaxf(fabsf(s[ng].z), fabsf(s[ng].w)));
#pragma unroll
            for (int d = 32; d > 0; d >>= 1) amax = fmaxf(amax, __shfl_xor(amax, d));
            float inv = (amax > 0.f) ? 32767.f/amax : 0.f;
            short4_t q;
            q.x = (short)__float2int_rn(s[ng].x*inv);
            q.y = (short)__float2int_rn(s[ng].y*inv);
            q.z = (short)__float2int_rn(s[ng].z*inv);
            q.w = (short)__float2int_rn(s[ng].w*inv);
            *(short4_t*)(WQ + ((size_t)(n0+ng)*OUT + o)*256 + lane*4) = q;
            if (lane == 0) wsc[(n0+ng)*OUT + o] = (amax > 0.f) ? amax/32767.f : 0.f;
        }
    }
}

__global__ __launch_bounds__(256) void bias_k(const float* __restrict__ emb,
                        const float* __restrict__ gbl, float* __restrict__ bn, int OUT)
{
    int idx = blockIdx.x*256 + threadIdx.x;
    if (idx >= N_NODES*OUT) return;
    int n = idx / OUT, o = idx % OUT;
    float s = 0.f;
#pragma unroll
    for (int e = 0; e < EMB; ++e) s += emb[n*EMB + e]*gbl[e*OUT + o];
    bn[idx] = s;
}

// C = A@B via mfma_f32_16x16x32_f16, f32-emulated (Ahi/Alo precomputed; B split
// hi/lo in staging; acc = Al*Bh + Ah*Bl + Ah*Bh). All jobs split-K=2 (ks halves
// written to out + ks*1M; consumers sum the pair). B operands TRANSPOSED [j][m]:
//   job 0: B = hT  f32              -> pAh
//   job 1: B = xqT i16 * xsc2[b][m] -> pAx
//   job 2: B = zhT f32              -> pAzh
// z = zoff + blockIdx.z in 0..5: job = z>>1, ks = z&1.
__global__ __launch_bounds__(256) void gemm16_k(
    const _Float16* __restrict__ Ahi, const _Float16* __restrict__ Alo,
    const float* __restrict__ hT, const short* __restrict__ xqTp,
    const float* __restrict__ xscp, const float* __restrict__ zhT,
    float* __restrict__ pAh, float* __restrict__ pAx, float* __restrict__ pAzh,
    int zoff)
{
    int z = zoff + blockIdx.z;
    int job = z >> 1, ks = z & 1;
    int kbase = ks << 9;
    float* out = ((job == 0) ? pAh : (job == 1) ? pAx : pAzh) + ((size_t)ks << 20);
    const float* BTf = (job == 0) ? hT : zhT;
    __shared__ _Float16 Ash[64*72];
    __shared__ _Float16 Asl[64*72];
    __shared__ _Float16 Bsh[64*72];
    __shared__ _Float16 Bsl[64*72];
    int t = threadIdx.x;
    int l = t & 63, w = t >> 6;
    int wr = w >> 1, wc = w & 1;
    int r0 = blockIdx.y*64, c0 = blockIdx.x*64;
    f32x4 acc[2][2];
#pragma unroll
    for (int i = 0; i < 2; ++i)
#pragma unroll
        for (int j = 0; j < 2; ++j) acc[i][j] = (f32x4){0.f,0.f,0.f,0.f};
    int arow = wr*32 + (l & 15);
    int brow = wc*32 + (l & 15);
    int koff = (l >> 4)*8;
    const float* sbase = xscp + ((c0 >> 6) << 10);   // per-(b,n) x scales, b = c0/64
    for (int k0 = kbase; k0 < kbase + 512; k0 += 64) {
        __syncthreads();
        // A tiles: coalesced f16x8
#pragma unroll
        for (int c = 0; c < 2; ++c) {
            int id = t + 256*c;
            int row = id >> 3, k8 = id & 7;
            *(f16x8*)(&Ash[row*72 + k8*8]) =
                *(const f16x8*)(&Ahi[(size_t)(r0+row)*1024 + k0 + k8*8]);
            *(f16x8*)(&Asl[row*72 + k8*8]) =
                *(const f16x8*)(&Alo[(size_t)(r0+row)*1024 + k0 + k8*8]);
        }
        // B tile from transposed source, coalesced along m
        if (job == 1) {
#pragma unroll
            for (int c = 0; c < 2; ++c) {
                int id = t + 256*c;
                int row = id >> 3, k8 = id & 7;
                short8_t q8 = *(const short8_t*)(xqTp + (size_t)(c0+row)*1024 + k0 + k8*8);
                float4 s0 = *(const float4*)(sbase + k0 + k8*8);
                float4 s1 = *(const float4*)(sbase + k0 + k8*8 + 4);
                float vv[8];
                vv[0] = (float)q8[0]*s0.x; vv[1] = (float)q8[1]*s0.y;
                vv[2] = (float)q8[2]*s0.z; vv[3] = (float)q8[3]*s0.w;
                vv[4] = (float)q8[4]*s1.x; vv[5] = (float)q8[5]*s1.y;
                vv[6] = (float)q8[6]*s1.z; vv[7] = (float)q8[7]*s1.w;
                f16x8 hi, lo;
#pragma unroll
                for (int i = 0; i < 8; ++i) {
                    _Float16 h = (_Float16)vv[i];
                    hi[i] = h;
                    lo[i] = (_Float16)(vv[i] - (float)h);
                }
                *(f16x8*)(&Bsh[row*72 + k8*8]) = hi;
                *(f16x8*)(&Bsl[row*72 + k8*8]) = lo;
            }
        } else {
#pragma unroll
            for (int c = 0; c < 4; ++c) {
                int id = t + 256*c;
                int row = id >> 4, kq = id & 15;
                float4 v = *(const float4*)(&BTf[(size_t)(c0+row)*1024 + k0 + kq*4]);
                float vv[4] = {v.x, v.y, v.z, v.w};
                f16x4 hi, lo;
#pragma unroll
                for (int i = 0; i < 4; ++i) {
                    _Float16 h = (_Float16)vv[i];
                    hi[i] = h;
                    lo[i] = (_Float16)(vv[i] - (float)h);
                }
                *(f16x4*)(&Bsh[row*72 + kq*4]) = hi;
                *(f16x4*)(&Bsl[row*72 + kq*4]) = lo;
            }
        }
        __syncthreads();
#pragma unroll
        for (int kk = 0; kk < 2; ++kk) {
            int ko = kk*32 + koff;
            f16x8 ah0 = *(const f16x8*)(&Ash[(size_t)arow*72 + ko]);
            f16x8 ah1 = *(const f16x8*)(&Ash[(size_t)(arow+16)*72 + ko]);
            f16x8 al0 = *(const f16x8*)(&Asl[(size_t)arow*72 + ko]);
            f16x8 al1 = *(const f16x8*)(&Asl[(size_t)(arow+16)*72 + ko]);
            f16x8 bh0 = *(const f16x8*)(&Bsh[(size_t)brow*72 + ko]);
            f16x8 bh1 = *(const f16x8*)(&Bsh[(size_t)(brow+16)*72 + ko]);
            f16x8 bl0 = *(const f16x8*)(&Bsl[(size_t)brow*72 + ko]);
            f16x8 bl1 = *(const f16x8*)(&Bsl[(size_t)(brow+16)*72 + ko]);
            acc[0][0] = __builtin_amdgcn_mfma_f32_16x16x32_f16(al0, bh0, acc[0][0], 0, 0, 0);
            acc[0][0] = __builtin_amdgcn_mfma_f32_16x16x32_f16(ah0, bl0, acc[0][0], 0, 0, 0);
            acc[0][0] = __builtin_amdgcn_mfma_f32_16x16x32_f16(ah0, bh0, acc[0][0], 0, 0, 0);
            acc[0][1] = __builtin_amdgcn_mfma_f32_16x16x32_f16(al0, bh1, acc[0][1], 0, 0, 0);
            acc[0][1] = __builtin_amdgcn_mfma_f32_16x16x32_f16(ah0, bl1, acc[0][1], 0, 0, 0);
            acc[0][1] = __builtin_amdgcn_mfma_f32_16x16x32_f16(ah0, bh1, acc[0][1], 0, 0, 0);
            acc[1][0] = __builtin_amdgcn_mfma_f32_16x16x32_f16(al1, bh0, acc[1][0], 0, 0, 0);
            acc[1][0] = __builtin_amdgcn_mfma_f32_16x16x32_f16(ah1, bl0, acc[1][0], 0, 0, 0);
            acc[1][0] = __builtin_amdgcn_mfma_f32_16x16x32_f16(ah1, bh0, acc[1][0], 0, 0, 0);
            acc[1][1] = __builtin_amdgcn_mfma_f32_16x16x32_f16(al1, bh1, acc[1][1], 0, 0, 0);
            acc[1][1] = __builtin_amdgcn_mfma_f32_16x16x32_f16(ah1, bl1, acc[1][1], 0, 0, 0);
            acc[1][1] = __builtin_amdgcn_mfma_f32_16x16x32_f16(ah1, bh1, acc[1][1], 0, 0, 0);
        }
    }
    // C/D layout: col = lane&15, row = 4*(lane>>4)+reg  [measured m89/m91]
#pragma unroll
    for (int fr = 0; fr < 2; ++fr)
#pragma unroll
        for (int fc = 0; fc < 2; ++fc) {
            int orow = r0 + wr*32 + fr*16 + ((l >> 4) << 2);
            int ocol = c0 + wc*32 + fc*16 + (l & 15);
#pragma unroll
            for (int i = 0; i < 4; ++i)
                out[(size_t)(orow+i)*1024 + ocol] = acc[fr][fc][i];
        }
}

// zr[n][b][o] = sigmoid([x,h,Ax,Ah]·Wq[n](o,:)·ws + bg); writes zhT[j][n]=z*h.
// 2x-output register blocking: thread = (o in [0,64), g in [0,4)) computes the
// PAIR {o, o+64} x 4 batches -> each inp float4 read feeds 2 outputs (LDS traffic
// halved vs 1-o version; inp reads are wave-broadcast, conflict-free).
template<int FIRST>
__global__ __launch_bounds__(256) void gate_k(
    const short* __restrict__ xqTp, const float* __restrict__ xscp,
    const float* __restrict__ hst, const float* __restrict__ pAx,
    const float* __restrict__ pAh, const short* __restrict__ WQ,
    const float* __restrict__ wsc, const float* __restrict__ bg,
    float* __restrict__ zr, float* __restrict__ zhT)
{
    __shared__ float inp[16*256];
    int n = ((blockIdx.x & 7) << 7) | (blockIdx.x >> 3);
    int t = threadIdx.x;
    size_t nb = (size_t)n*1024;
    for (int i = t; i < 1024; i += 256) {
        int b = i >> 6, c = i & 63;
        float sx = xscp[(b << 10) + n];
        inp[b*256 + c]       = (float)xqTp[(size_t)i*1024 + n] * sx;
        inp[b*256 + 64 + c]  = FIRST ? 0.f : hst[nb + i];
        inp[b*256 + 128 + c] = pAx[nb + i] + pAx[nb + i + 1048576];
        inp[b*256 + 192 + c] = FIRST ? 0.f : (pAh[nb + i] + pAh[nb + i + 1048576]);
    }
    __syncthreads();
    int o = t & 63, g = t >> 6;          // z-col o, r-col o+64; batches 4g..4g+3
    const short* wp0 = WQ + ((size_t)n*128 + o)*256;
    const short* wp1 = WQ + ((size_t)n*128 + o + 64)*256;
    float ws0 = wsc[n*128 + o],   ws1 = wsc[n*128 + o + 64];
    float bi0 = bg[n*128 + o],    bi1 = bg[n*128 + o + 64];
    float acc0[4], acc1[4];
#pragma unroll
    for (int u = 0; u < 4; ++u) { acc0[u] = 0.f; acc1[u] = 0.f; }
    for (int k0 = 0; k0 < 256; k0 += 4) {
        short4_t wa = *(const short4_t*)(wp0 + k0);
        short4_t wb = *(const short4_t*)(wp1 + k0);
        float a0 = (float)wa.x, a1 = (float)wa.y, a2 = (float)wa.z, a3 = (float)wa.w;
        float b0 = (float)wb.x, b1 = (float)wb.y, b2 = (float)wb.z, b3 = (float)wb.w;
#pragma unroll
        for (int u = 0; u < 4; ++u) {
            float4 iv = *(const float4*)(&inp[(g*4 + u)*256 + k0]);
            acc0[u] += a0*iv.x + a1*iv.y + a2*iv.z + a3*iv.w;
            acc1[u] += b0*iv.x + b1*iv.y + b2*iv.z + b3*iv.w;
        }
    }
#pragma unroll
    for (int u = 0; u < 4; ++u) {
        int b = g*4 + u;
        float zv = 1.f/(1.f + expf(-(acc0[u]*ws0 + bi0)));
        float rv = 1.f/(1.f + expf(-(acc1[u]*ws1 + bi1)));
        zr[((size_t)n*16 + b)*128 + o] = zv;
        zr[((size_t)n*16 + b)*128 + 64 + o] = rv;
        if (!FIRST)
            zhT[(size_t)(b*64 + o)*1024 + n] = zv * inp[b*256 + 64 + o];
    }
}

// h_new = r*h + (1-r)*tanh([x, z*h, Ax, Azh]·Wu[n]·ws + bu); writes hst rows,
// hT columns, (WX) next-layer xqT i16 columns. 2x-output register blocking:
// thread = (o in [0,32), g in [0,8)) computes {o, o+32} x batches {2g, 2g+1}.
template<int FIRST, int WX>
__global__ __launch_bounds__(256) void upd_k(
    short* __restrict__ xqTp, const float* __restrict__ xscp,
    float* __restrict__ hst, const float* __restrict__ pAx,
    const float* __restrict__ pAzh, const float* __restrict__ zr,
    const short* __restrict__ WQ, const float* __restrict__ wsc,
    const float* __restrict__ bu, float* __restrict__ hT)
{
    __shared__ float inp[16*256];
    int n = ((blockIdx.x & 7) << 7) | (blockIdx.x >> 3);
    int t = threadIdx.x;
    size_t nb = (size_t)n*1024;
    for (int i = t; i < 1024; i += 256) {
        int b = i >> 6, c = i & 63;
        float sx = xscp[(b << 10) + n];
        float hv = FIRST ? 0.f : hst[nb + i];
        float zv = zr[((size_t)n*16 + b)*128 + c];
        inp[b*256 + c]       = (float)xqTp[(size_t)i*1024 + n] * sx;
        inp[b*256 + 64 + c]  = zv * hv;
        inp[b*256 + 128 + c] = pAx[nb + i] + pAx[nb + i + 1048576];
        inp[b*256 + 192 + c] = FIRST ? 0.f : (pAzh[nb + i] + pAzh[nb + i + 1048576]);
    }
    __syncthreads();
    int o = t & 31, g = t >> 5;          // outputs {o, o+32}; batches {2g, 2g+1}
    const short* wp0 = WQ + ((size_t)n*64 + o)*256;
    const short* wp1 = WQ + ((size_t)n*64 + o + 32)*256;
    float ws0 = wsc[n*64 + o],  ws1 = wsc[n*64 + o + 32];
    float bi0 = bu[n*64 + o],   bi1 = bu[n*64 + o + 32];
    float acc0[2], acc1[2];
#pragma unroll
    for (int u = 0; u < 2; ++u) { acc0[u] = 0.f; acc1[u] = 0.f; }
    for (int k0 = 0; k0 < 256; k0 += 4) {
        short4_t wa = *(const short4_t*)(wp0 + k0);
        short4_t wb = *(const short4_t*)(wp1 + k0);
        float a0 = (float)wa.x, a1 = (float)wa.y, a2 = (float)wa.z, a3 = (float)wa.w;
        float b0 = (float)wb.x, b1 = (float)wb.y, b2 = (float)wb.z, b3 = (float)wb.w;
#pragma unroll
        for (int u = 0; u < 2; ++u) {
            float4 iv = *(const float4*)(&inp[(g*2 + u)*256 + k0]);
            acc0[u] += a0*iv.x + a1*iv.y + a2*iv.z + a3*iv.w;
            acc1[u] += b0*iv.x + b1*iv.y + b2*iv.z + b3*iv.w;
        }
    }
#pragma unroll
    for (int u = 0; u < 2; ++u) {
        int b = g*2 + u;
#pragma unroll
        for (int q = 0; q < 2; ++q) {
            int oo = o + q*32;
            float av = q ? acc1[u] : acc0[u];
            float wsv = q ? ws1 : ws0;
            float biv = q ? bi1 : bi0;
            float r = zr[((size_t)n*16 + b)*128 + 64 + oo];
            float hold = FIRST ? 0.f : hst[nb + b*64 + oo];
            float hc = tanhf(av*wsv + biv);
            float hn = r*hold + (1.f - r)*hc;
            hst[nb + b*64 + oo] = hn;
            hT[(size_t)(b*64 + oo)*1024 + n] = hn;
            if (WX) xqTp[(size_t)(b*64 + oo)*1024 + n] = (short)__float2int_rn(hn*32767.f);
        }
    }
}

// out[b][o][n] = h[n][b][:]·ecw[o][:] + ecb[o]
__global__ __launch_bounds__(256) void endconv_k(
    const float* __restrict__ hst, const float* __restrict__ ecw,
    const float* __restrict__ ecb, float* __restrict__ out)
{
    int idx = blockIdx.x*256 + threadIdx.x;
    int n = idx & 1023;
    int o = (idx >> 10) % HOR;
    int b = idx / (HOR*1024);
    float s = ecb[o];
#pragma unroll
    for (int hh = 0; hh < 64; ++hh)
        s += hst[((size_t)n*16 + b)*64 + hh] * ecw[o*64 + hh];
    out[idx] = s;
}

extern "C" void kernel_launch(void* const* d_in, const int* in_sizes, int n_in,
                              void* d_out, int out_size, void* d_ws, size_t ws_size,
                              hipStream_t stream)
{
    const float* source = (const float*)d_in[0];
    const float* emb    = (const float*)d_in[2];
    const float* vw     = (const float*)d_in[3];
    const float* gate_w = (const float*)d_in[4];
    const float* gate_b = (const float*)d_in[5];
    const float* upd_w  = (const float*)d_in[6];
    const float* upd_b  = (const float*)d_in[7];
    const float* ecw    = (const float*)d_in[8];
    const float* ecb    = (const float*)d_in[9];
    float* out = (float*)d_out;

    // ---- workspace carve: ~205 MB ----
    char* p = (char*)d_ws;
    _Float16* Ahi = (_Float16*)p; p += (size_t)1048576*2;    //   2.0 MB
    _Float16* Alo = (_Float16*)p; p += (size_t)1048576*2;    //   2.0 MB
    short* WgQ  = (short*)p;  p += (size_t)33554432*2;       //  64.0 MB
    short* WuQ  = (short*)p;  p += (size_t)16777216*2;       //  32.0 MB
    float* swg  = (float*)p;  p += (size_t)131072*4;         //   0.5 MB
    float* swu  = (float*)p;  p += (size_t)65536*4;          //   0.25 MB
    float* bgn  = (float*)p;  p += (size_t)131072*4;         //   0.5 MB
    float* bun  = (float*)p;  p += (size_t)65536*4;          //   0.25 MB
    short* xqT  = (short*)p;  p += (size_t)25165824*2;       //  48.0 MB  [p][j][n] i16
    float* xscA = (float*)p;  p += (size_t)393216*4;         //   1.5 MB
    float* xscB = (float*)p;  p += (size_t)393216*4;         //   1.5 MB
    float* hbuf = (float*)p;  p += (size_t)1048576*4;        //   4.0 MB
    float* hT   = (float*)p;  p += (size_t)1048576*4;        //   4.0 MB
    float* zrb  = (float*)p;  p += (size_t)2097152*4;        //   8.0 MB
    float* zhT  = (float*)p;  p += (size_t)1048576*4;        //   4.0 MB
    float* pAh  = (float*)p;  p += (size_t)2097152*4;        //   8.0 MB  split-K pair
    float* pAx  = (float*)p;  p += (size_t)2097152*4;        //   8.0 MB  split-K pair
    float* pAzh = (float*)p;  p += (size_t)2097152*4;        //   8.0 MB  split-K pair
    float* gwT  = pAzh;   // 2 MB scratch, aliases pAzh (dead during layer setup)

    embedq4_k<<<dim3(16,24), 256, 0, stream>>>(source, vw, xqT, xscA);
    adj_k<<<1024, 256, 0, stream>>>(emb, Ahi, Alo);
    fill_k<<<1536, 256, 0, stream>>>(xscB, 1.f/32767.f, 393216);

    for (int l = 0; l < 2; ++l) {
        const float* xsc2 = (l == 0) ? xscA : xscB;
        wtrans_k<128><<<2048, 256, 0, stream>>>(gate_w + (size_t)l*524288, gwT);
        wnodeq2_k<128><<<dim3(256,4), 256, 0, stream>>>(emb, gwT, WgQ, swg);
        wtrans_k<64><<<1024, 256, 0, stream>>>(upd_w + (size_t)l*262144, gwT);
        wnodeq2_k<64><<<dim3(256,4), 256, 0, stream>>>(emb, gwT, WuQ, swu);
        bias_k<<<512, 256, 0, stream>>>(emb, gate_b + l*2048, bgn, 128);
        bias_k<<<256, 256, 0, stream>>>(emb, upd_b + l*1024, bun, 64);
        for (int ps = 0; ps < PWIN; ++ps) {
            short* xqT_p = xqT + ((size_t)ps << 20);
            const float* xsc_p = xsc2 + (size_t)ps*16384;
            if (ps == 0) {
                // h == 0: only A@x needed (job 1, both K-halves)
                gemm16_k<<<dim3(16,16,2), 256, 0, stream>>>(Ahi, Alo, hT, xqT_p, xsc_p, zhT, pAh, pAx, pAzh, 2);
                gate_k<1><<<1024, 256, 0, stream>>>(xqT_p, xsc_p, hbuf, pAx, pAh, WgQ, swg, bgn, zrb, zhT);
                if (l == 0)
                    upd_k<1,1><<<1024, 256, 0, stream>>>(xqT_p, xsc_p, hbuf, pAx, pAzh, zrb, WuQ, swu, bun, hT);
                else
                    upd_k<1,0><<<1024, 256, 0, stream>>>(xqT_p, xsc_p, hbuf, pAx, pAzh, zrb, WuQ, swu, bun, hT);
            } else {
                gemm16_k<<<dim3(16,16,4), 256, 0, stream>>>(Ahi, Alo, hT, xqT_p, xsc_p, zhT, pAh, pAx, pAzh, 0);
                gate_k<0><<<1024, 256, 0, stream>>>(xqT_p, xsc_p, hbuf, pAx, pAh, WgQ, swg, bgn, zrb, zhT);
                gemm16_k<<<dim3(16,16,2), 256, 0, stream>>>(Ahi, Alo, hT, xqT_p, xsc_p, zhT, pAh, pAx, pAzh, 4);
                if (l == 0)
                    upd_k<0,1><<<1024, 256, 0, stream>>>(xqT_p, xsc_p, hbuf, pAx, pAzh, zrb, WuQ, swu, bun, hT);
                else
                    upd_k<0,0><<<1024, 256, 0, stream>>>(xqT_p, xsc_p, hbuf, pAx, pAzh, zrb, WuQ, swu, bun, hT);
            }
        }
    }
    endconv_k<<<768, 256, 0, stream>>>(hbuf, ecw, ecb, out);
}

// Round 11
// 5217.033 us; speedup vs baseline: 2.7201x; 1.2893x over previous
//
#include <hip/hip_runtime.h>
#include <math.h>

#define N_NODES 1024
#define HID 64
#define BATCH 16
#define TSTEPS 288
#define PWIN 24
#define PL 12
#define EMB 16
#define HOR 12

typedef __attribute__((ext_vector_type(4))) short short4_t;
typedef __attribute__((ext_vector_type(8))) short short8_t;
typedef _Float16 f16x8 __attribute__((ext_vector_type(8)));
typedef _Float16 f16x4 __attribute__((ext_vector_type(4)));
typedef float f32x4 __attribute__((ext_vector_type(4)));

__global__ __launch_bounds__(256) void fill_k(float* p, float v, int n) {
    int i = blockIdx.x*256 + threadIdx.x;
    if (i < n) p[i] = v;
}

// block per (ngrp, p): lane = n (coalesced stores), wave wid covers b = 4*wid..+3.
// Two-pass per b (amax pass, quantize pass) with 8-wide register chunks.
__global__ __launch_bounds__(256) void embedq4_k(
    const float* __restrict__ src, const float* __restrict__ vw,
    short* __restrict__ xqT, float* __restrict__ xsc2)
{
    int p = blockIdx.y;
    int n0 = blockIdx.x * 64;
    int t = threadIdx.x;
    int lane = t & 63, wid = t >> 6;
    __shared__ float sv[192][64];     // [b*12+tt][n]
    __shared__ float wvs[PL*HID];
    __shared__ float pe[64];
    for (int r = wid; r < 192; r += 4) {
        int b = r / 12, tt = r - b*12;
        sv[r][lane] = src[((size_t)b*TSTEPS + p*PL + tt)*N_NODES + n0 + lane];
    }
    for (int i = t; i < PL*HID; i += 256) wvs[i] = vw[i];
    if (t < 64) {
        float d = expf(-(float)(t & ~1) * (float)(9.210340371976184/64.0));
        float arg = (float)p * d;
        pe[t] = (t & 1) ? cosf(arg) : sinf(arg);
    }
    __syncthreads();
#pragma unroll 1
    for (int bb = 0; bb < 4; ++bb) {
        int b = wid*4 + bb;
        float svr[12];
#pragma unroll
        for (int tt = 0; tt < 12; ++tt) svr[tt] = sv[b*12 + tt][lane];
        float amax = 0.f;
#pragma unroll 1
        for (int h0 = 0; h0 < 64; h0 += 8) {
#pragma unroll
            for (int hh = 0; hh < 8; ++hh) {
                int h = h0 + hh;
                float d = pe[h];
#pragma unroll
                for (int tt = 0; tt < 12; ++tt) d += svr[tt] * wvs[tt*HID + h];
                amax = fmaxf(amax, fabsf(d));
            }
        }
        float inv = (amax > 0.f) ? 32767.f/amax : 0.f;
        short* xp = xqT + ((size_t)p << 20) + (size_t)b*64*1024 + n0 + lane;
#pragma unroll 1
        for (int h0 = 0; h0 < 64; h0 += 8) {
#pragma unroll
            for (int hh = 0; hh < 8; ++hh) {
                int h = h0 + hh;
                float d = pe[h];
#pragma unroll
                for (int tt = 0; tt < 12; ++tt) d += svr[tt] * wvs[tt*HID + h];
                xp[(size_t)h*1024] = (short)__float2int_rn(d*inv);
            }
        }
        xsc2[((p*16 + b) << 10) + n0 + lane] = (amax > 0.f) ? amax/32767.f : 0.f;
    }
}

// A[n][m] = softmax_m(relu(emb[n]·emb[m])), written as f16 hi/lo pair (compensated)
__global__ __launch_bounds__(256) void adj_k(const float* __restrict__ emb,
    _Float16* __restrict__ Ahi, _Float16* __restrict__ Alo)
{
    __shared__ float en[EMB];
    __shared__ float red[256];
    int n = blockIdx.x, t = threadIdx.x;
    if (t < EMB) en[t] = emb[n*EMB + t];
    __syncthreads();
    float v[4]; float mx = 0.f;
#pragma unroll
    for (int q = 0; q < 4; ++q) {
        int m = q*256 + t;
        float dot = 0.f;
#pragma unroll
        for (int e = 0; e < EMB; ++e) dot += en[e]*emb[m*EMB + e];
        v[q] = fmaxf(dot, 0.f);
        mx = fmaxf(mx, v[q]);
    }
    red[t] = mx; __syncthreads();
    for (int s2 = 128; s2 > 0; s2 >>= 1) {
        if (t < s2) red[t] = fmaxf(red[t], red[t + s2]);
        __syncthreads();
    }
    mx = red[0]; __syncthreads();
    float sum = 0.f;
#pragma unroll
    for (int q = 0; q < 4; ++q) { v[q] = expf(v[q] - mx); sum += v[q]; }
    red[t] = sum; __syncthreads();
    for (int s2 = 128; s2 > 0; s2 >>= 1) {
        if (t < s2) red[t] += red[t + s2];
        __syncthreads();
    }
    float inv = 1.f / red[0];
#pragma unroll
    for (int q = 0; q < 4; ++q) {
        float av = v[q]*inv;
        _Float16 hi = (_Float16)av;
        size_t idx = (size_t)n*N_NODES + q*256 + t;
        Ahi[idx] = hi;
        Alo[idx] = (_Float16)(av - (float)hi);
    }
}

// gwT[e][o][kc] <- gwl[e][kc][o]
template<int OUT>
__global__ __launch_bounds__(256) void wtrans_k(
    const float* __restrict__ gwl, float* __restrict__ gwT)
{
    int idx = blockIdx.x*256 + threadIdx.x;
    int kc = idx & 255;
    int rest = idx >> 8;
    int o = rest % OUT;
    int e = rest / OUT;
    gwT[idx] = gwl[((size_t)e*256 + kc)*OUT + o];
}

// W[n](o,kc) = sum_e emb[n][e]*gwT[e][o][kc], i16 with per-(n,o) row scale.
// NEW output layout [n][kc4][OUT][4] (4 consecutive k's per o) so the consumers'
// weight loads are lane-coalesced (o contiguous). Same stores, new index.
template<int OUT>
__global__ __launch_bounds__(256) void wnodeq2_k(
    const float* __restrict__ emb, const float* __restrict__ gwT,
    short* __restrict__ WQ, float* __restrict__ wsc)
{
    int t = threadIdx.x;
    int n0 = blockIdx.x * 4;
    int oh = blockIdx.y;
    int lane = t & 63, w = t >> 6;     // lane = kc quad index (kc = lane*4..+3)
    __shared__ float se[4][EMB];
    if (t < 4*EMB) se[t >> 4][t & 15] = emb[(n0 + (t >> 4))*EMB + (t & 15)];
    __syncthreads();
    for (int o = oh*(OUT/4) + w; o < (oh+1)*(OUT/4); o += 4) {
        const float* gp = gwT + (size_t)o*256 + lane*4;
        float4 s[4];
#pragma unroll
        for (int ng = 0; ng < 4; ++ng) s[ng] = make_float4(0.f, 0.f, 0.f, 0.f);
#pragma unroll
        for (int e = 0; e < EMB; ++e) {
            float4 g = *(const float4*)(gp + (size_t)e*(OUT*256));
#pragma unroll
            for (int ng = 0; ng < 4; ++ng) {
                float c = se[ng][e];
                s[ng].x += c*g.x; s[ng].y += c*g.y; s[ng].z += c*g.z; s[ng].w += c*g.w;
            }
        }
#pragma unroll
        for (int ng = 0; ng < 4; ++ng) {
            float amax = fmaxf(fmaxf(fabsf(s[ng].x), fabsf(s[ng].y)),
                               fmaxf(fabsf(s[ng].z), fabsf(s[ng].w)));
#pragma unroll
            for (int d = 32; d > 0; d >>= 1) amax = fmaxf(amax, __shfl_xor(amax, d));
            float inv = (amax > 0.f) ? 32767.f/amax : 0.f;
            short4_t q;
            q.x = (short)__float2int_rn(s[ng].x*inv);
            q.y = (short)__float2int_rn(s[ng].y*inv);
            q.z = (short)__float2int_rn(s[ng].z*inv);
            q.w = (short)__float2int_rn(s[ng].w*inv);
            // [n][kc4=lane][OUT][4]
            *(short4_t*)(WQ + (((size_t)(n0+ng)*64 + lane)*OUT + o)*4) = q;
            if (lane == 0) wsc[(n0+ng)*OUT + o] = (amax > 0.f) ? amax/32767.f : 0.f;
        }
    }
}

__global__ __launch_bounds__(256) void bias_k(const float* __restrict__ emb,
                        const float* __restrict__ gbl, float* __restrict__ bn, int OUT)
{
    int idx = blockIdx.x*256 + threadIdx.x;
    if (idx >= N_NODES*OUT) return;
    int n = idx / OUT, o = idx % OUT;
    float s = 0.f;
#pragma unroll
    for (int e = 0; e < EMB; ++e) s += emb[n*EMB + e]*gbl[e*OUT + o];
    bn[idx] = s;
}

// C = A@B via mfma_f32_16x16x32_f16, f32-emulated (Ahi/Alo precomputed; B split
// hi/lo in staging; acc = Al*Bh + Ah*Bl + Ah*Bh). All jobs split-K=2 (ks halves
// written to out + ks*1M; consumers sum the pair). B operands TRANSPOSED [j][m]:
//   job 0: B = hT  f32              -> pAh
//   job 1: B = xqT i16 * xsc2[b][m] -> pAx
//   job 2: B = zhT f32              -> pAzh
// z = zoff + blockIdx.z in 0..5: job = z>>1, ks = z&1.
__global__ __launch_bounds__(256) void gemm16_k(
    const _Float16* __restrict__ Ahi, const _Float16* __restrict__ Alo,
    const float* __restrict__ hT, const short* __restrict__ xqTp,
    const float* __restrict__ xscp, const float* __restrict__ zhT,
    float* __restrict__ pAh, float* __restrict__ pAx, float* __restrict__ pAzh,
    int zoff)
{
    int z = zoff + blockIdx.z;
    int job = z >> 1, ks = z & 1;
    int kbase = ks << 9;
    float* out = ((job == 0) ? pAh : (job == 1) ? pAx : pAzh) + ((size_t)ks << 20);
    const float* BTf = (job == 0) ? hT : zhT;
    __shared__ _Float16 Ash[64*72];
    __shared__ _Float16 Asl[64*72];
    __shared__ _Float16 Bsh[64*72];
    __shared__ _Float16 Bsl[64*72];
    int t = threadIdx.x;
    int l = t & 63, w = t >> 6;
    int wr = w >> 1, wc = w & 1;
    int r0 = blockIdx.y*64, c0 = blockIdx.x*64;
    f32x4 acc[2][2];
#pragma unroll
    for (int i = 0; i < 2; ++i)
#pragma unroll
        for (int j = 0; j < 2; ++j) acc[i][j] = (f32x4){0.f,0.f,0.f,0.f};
    int arow = wr*32 + (l & 15);
    int brow = wc*32 + (l & 15);
    int koff = (l >> 4)*8;
    const float* sbase = xscp + ((c0 >> 6) << 10);   // per-(b,n) x scales, b = c0/64
    for (int k0 = kbase; k0 < kbase + 512; k0 += 64) {
        __syncthreads();
        // A tiles: coalesced f16x8
#pragma unroll
        for (int c = 0; c < 2; ++c) {
            int id = t + 256*c;
            int row = id >> 3, k8 = id & 7;
            *(f16x8*)(&Ash[row*72 + k8*8]) =
                *(const f16x8*)(&Ahi[(size_t)(r0+row)*1024 + k0 + k8*8]);
            *(f16x8*)(&Asl[row*72 + k8*8]) =
                *(const f16x8*)(&Alo[(size_t)(r0+row)*1024 + k0 + k8*8]);
        }
        // B tile from transposed source, coalesced along m
        if (job == 1) {
#pragma unroll
            for (int c = 0; c < 2; ++c) {
                int id = t + 256*c;
                int row = id >> 3, k8 = id & 7;
                short8_t q8 = *(const short8_t*)(xqTp + (size_t)(c0+row)*1024 + k0 + k8*8);
                float4 s0 = *(const float4*)(sbase + k0 + k8*8);
                float4 s1 = *(const float4*)(sbase + k0 + k8*8 + 4);
                float vv[8];
                vv[0] = (float)q8[0]*s0.x; vv[1] = (float)q8[1]*s0.y;
                vv[2] = (float)q8[2]*s0.z; vv[3] = (float)q8[3]*s0.w;
                vv[4] = (float)q8[4]*s1.x; vv[5] = (float)q8[5]*s1.y;
                vv[6] = (float)q8[6]*s1.z; vv[7] = (float)q8[7]*s1.w;
                f16x8 hi, lo;
#pragma unroll
                for (int i = 0; i < 8; ++i) {
                    _Float16 h = (_Float16)vv[i];
                    hi[i] = h;
                    lo[i] = (_Float16)(vv[i] - (float)h);
                }
                *(f16x8*)(&Bsh[row*72 + k8*8]) = hi;
                *(f16x8*)(&Bsl[row*72 + k8*8]) = lo;
            }
        } else {
#pragma unroll
            for (int c = 0; c < 4; ++c) {
                int id = t + 256*c;
                int row = id >> 4, kq = id & 15;
                float4 v = *(const float4*)(&BTf[(size_t)(c0+row)*1024 + k0 + kq*4]);
                float vv[4] = {v.x, v.y, v.z, v.w};
                f16x4 hi, lo;
#pragma unroll
                for (int i = 0; i < 4; ++i) {
                    _Float16 h = (_Float16)vv[i];
                    hi[i] = h;
                    lo[i] = (_Float16)(vv[i] - (float)h);
                }
                *(f16x4*)(&Bsh[row*72 + kq*4]) = hi;
                *(f16x4*)(&Bsl[row*72 + kq*4]) = lo;
            }
        }
        __syncthreads();
#pragma unroll
        for (int kk = 0; kk < 2; ++kk) {
            int ko = kk*32 + koff;
            f16x8 ah0 = *(const f16x8*)(&Ash[(size_t)arow*72 + ko]);
            f16x8 ah1 = *(const f16x8*)(&Ash[(size_t)(arow+16)*72 + ko]);
            f16x8 al0 = *(const f16x8*)(&Asl[(size_t)arow*72 + ko]);
            f16x8 al1 = *(const f16x8*)(&Asl[(size_t)(arow+16)*72 + ko]);
            f16x8 bh0 = *(const f16x8*)(&Bsh[(size_t)brow*72 + ko]);
            f16x8 bh1 = *(const f16x8*)(&Bsh[(size_t)(brow+16)*72 + ko]);
            f16x8 bl0 = *(const f16x8*)(&Bsl[(size_t)brow*72 + ko]);
            f16x8 bl1 = *(const f16x8*)(&Bsl[(size_t)(brow+16)*72 + ko]);
            acc[0][0] = __builtin_amdgcn_mfma_f32_16x16x32_f16(al0, bh0, acc[0][0], 0, 0, 0);
            acc[0][0] = __builtin_amdgcn_mfma_f32_16x16x32_f16(ah0, bl0, acc[0][0], 0, 0, 0);
            acc[0][0] = __builtin_amdgcn_mfma_f32_16x16x32_f16(ah0, bh0, acc[0][0], 0, 0, 0);
            acc[0][1] = __builtin_amdgcn_mfma_f32_16x16x32_f16(al0, bh1, acc[0][1], 0, 0, 0);
            acc[0][1] = __builtin_amdgcn_mfma_f32_16x16x32_f16(ah0, bl1, acc[0][1], 0, 0, 0);
            acc[0][1] = __builtin_amdgcn_mfma_f32_16x16x32_f16(ah0, bh1, acc[0][1], 0, 0, 0);
            acc[1][0] = __builtin_amdgcn_mfma_f32_16x16x32_f16(al1, bh0, acc[1][0], 0, 0, 0);
            acc[1][0] = __builtin_amdgcn_mfma_f32_16x16x32_f16(ah1, bl0, acc[1][0], 0, 0, 0);
            acc[1][0] = __builtin_amdgcn_mfma_f32_16x16x32_f16(ah1, bh0, acc[1][0], 0, 0, 0);
            acc[1][1] = __builtin_amdgcn_mfma_f32_16x16x32_f16(al1, bh1, acc[1][1], 0, 0, 0);
            acc[1][1] = __builtin_amdgcn_mfma_f32_16x16x32_f16(ah1, bl1, acc[1][1], 0, 0, 0);
            acc[1][1] = __builtin_amdgcn_mfma_f32_16x16x32_f16(ah1, bh1, acc[1][1], 0, 0, 0);
        }
    }
    // C/D layout: col = lane&15, row = 4*(lane>>4)+reg  [measured m89/m91]
#pragma unroll
    for (int fr = 0; fr < 2; ++fr)
#pragma unroll
        for (int fc = 0; fc < 2; ++fc) {
            int orow = r0 + wr*32 + fr*16 + ((l >> 4) << 2);
            int ocol = c0 + wc*32 + fc*16 + (l & 15);
#pragma unroll
            for (int i = 0; i < 4; ++i)
                out[(size_t)(orow+i)*1024 + ocol] = acc[fr][fc][i];
        }
}

// zr[n][b][o] = sigmoid([x,h,Ax,Ah]·Wq[n](o,:)·ws + bg); writes zhT[j][n]=z*h.
// R7 thread mapping (o = t&127, inp reads wave-broadcast); weight loads now
// COALESCED via the [n][kc4][128][4] layout (lane-consecutive o, 8B/lane).
template<int FIRST>
__global__ __launch_bounds__(256) void gate_k(
    const short* __restrict__ xqTp, const float* __restrict__ xscp,
    const float* __restrict__ hst, const float* __restrict__ pAx,
    const float* __restrict__ pAh, const short* __restrict__ WQ,
    const float* __restrict__ wsc, const float* __restrict__ bg,
    float* __restrict__ zr, float* __restrict__ zhT)
{
    __shared__ float inp[16*256];
    int n = ((blockIdx.x & 7) << 7) | (blockIdx.x >> 3);
    int t = threadIdx.x;
    size_t nb = (size_t)n*1024;
    for (int i = t; i < 1024; i += 256) {
        int b = i >> 6, c = i & 63;
        float sx = xscp[(b << 10) + n];
        inp[b*256 + c]       = (float)xqTp[(size_t)i*1024 + n] * sx;
        inp[b*256 + 64 + c]  = FIRST ? 0.f : hst[nb + i];
        inp[b*256 + 128 + c] = pAx[nb + i] + pAx[nb + i + 1048576];
        inp[b*256 + 192 + c] = FIRST ? 0.f : (pAh[nb + i] + pAh[nb + i + 1048576]);
    }
    __syncthreads();
    int o = t & 127, g = t >> 7;
    const short* wp = WQ + (size_t)n*32768 + o*4;   // [n][kc4][128][4]
    float ws = wsc[n*128 + o];
    float bias = bg[n*128 + o];
    float acc[8];
#pragma unroll
    for (int u = 0; u < 8; ++u) acc[u] = 0.f;
    for (int k0 = 0; k0 < 256; k0 += 4) {
        short4_t w4 = *(const short4_t*)(wp + (size_t)(k0 >> 2)*512);
        float w0 = (float)w4.x, w1 = (float)w4.y, w2 = (float)w4.z, w3 = (float)w4.w;
#pragma unroll
        for (int u = 0; u < 8; ++u) {
            float4 iv = *(const float4*)(&inp[(g*8 + u)*256 + k0]);
            acc[u] += w0*iv.x + w1*iv.y + w2*iv.z + w3*iv.w;
        }
    }
#pragma unroll
    for (int u = 0; u < 8; ++u) {
        int b = g*8 + u;
        float pre = acc[u]*ws + bias;
        float val = 1.f/(1.f + expf(-pre));
        zr[((size_t)n*16 + b)*128 + o] = val;
        if (!FIRST && o < 64)
            zhT[(size_t)(b*64 + o)*1024 + n] = val * inp[b*256 + 64 + o];
    }
}

// h_new = r*h + (1-r)*tanh([x, z*h, Ax, Azh]·Wu[n]·ws + bu); writes hst rows,
// hT columns, (WX) next-layer xqT i16 columns. R7 mapping; coalesced weights
// via [n][kc4][64][4] layout.
template<int FIRST, int WX>
__global__ __launch_bounds__(256) void upd_k(
    short* __restrict__ xqTp, const float* __restrict__ xscp,
    float* __restrict__ hst, const float* __restrict__ pAx,
    const float* __restrict__ pAzh, const float* __restrict__ zr,
    const short* __restrict__ WQ, const float* __restrict__ wsc,
    const float* __restrict__ bu, float* __restrict__ hT)
{
    __shared__ float inp[16*256];
    int n = ((blockIdx.x & 7) << 7) | (blockIdx.x >> 3);
    int t = threadIdx.x;
    size_t nb = (size_t)n*1024;
    for (int i = t; i < 1024; i += 256) {
        int b = i >> 6, c = i & 63;
        float sx = xscp[(b << 10) + n];
        float hv = FIRST ? 0.f : hst[nb + i];
        float zv = zr[((size_t)n*16 + b)*128 + c];
        inp[b*256 + c]       = (float)xqTp[(size_t)i*1024 + n] * sx;
        inp[b*256 + 64 + c]  = zv * hv;
        inp[b*256 + 128 + c] = pAx[nb + i] + pAx[nb + i + 1048576];
        inp[b*256 + 192 + c] = FIRST ? 0.f : (pAzh[nb + i] + pAzh[nb + i + 1048576]);
    }
    __syncthreads();
    int o = t & 63, g = t >> 6;
    const short* wp = WQ + (size_t)n*16384 + o*4;   // [n][kc4][64][4]
    float ws = wsc[n*64 + o];
    float bias = bu[n*64 + o];
    float acc[4];
#pragma unroll
    for (int u = 0; u < 4; ++u) acc[u] = 0.f;
    for (int k0 = 0; k0 < 256; k0 += 4) {
        short4_t w4 = *(const short4_t*)(wp + (size_t)(k0 >> 2)*256);
        float w0 = (float)w4.x, w1 = (float)w4.y, w2 = (float)w4.z, w3 = (float)w4.w;
#pragma unroll
        for (int u = 0; u < 4; ++u) {
            float4 iv = *(const float4*)(&inp[(g*4 + u)*256 + k0]);
            acc[u] += w0*iv.x + w1*iv.y + w2*iv.z + w3*iv.w;
        }
    }
#pragma unroll
    for (int u = 0; u < 4; ++u) {
        int b = g*4 + u;
        float r = zr[((size_t)n*16 + b)*128 + 64 + o];
        float hold = FIRST ? 0.f : hst[nb + b*64 + o];
        float hc = tanhf(acc[u]*ws + bias);
        float hn = r*hold + (1.f - r)*hc;
        hst[nb + b*64 + o] = hn;
        hT[(size_t)(b*64 + o)*1024 + n] = hn;
        if (WX) xqTp[(size_t)(b*64 + o)*1024 + n] = (short)__float2int_rn(hn*32767.f);
    }
}

// out[b][o][n] = h[n][b][:]·ecw[o][:] + ecb[o]
__global__ __launch_bounds__(256) void endconv_k(
    const float* __restrict__ hst, const float* __restrict__ ecw,
    const float* __restrict__ ecb, float* __restrict__ out)
{
    int idx = blockIdx.x*256 + threadIdx.x;
    int n = idx & 1023;
    int o = (idx >> 10) % HOR;
    int b = idx / (HOR*1024);
    float s = ecb[o];
#pragma unroll
    for (int hh = 0; hh < 64; ++hh)
        s += hst[((size_t)n*16 + b)*64 + hh] * ecw[o*64 + hh];
    out[idx] = s;
}

extern "C" void kernel_launch(void* const* d_in, const int* in_sizes, int n_in,
                              void* d_out, int out_size, void* d_ws, size_t ws_size,
                              hipStream_t stream)
{
    const float* source = (const float*)d_in[0];
    const float* emb    = (const float*)d_in[2];
    const float* vw     = (const float*)d_in[3];
    const float* gate_w = (const float*)d_in[4];
    const float* gate_b = (const float*)d_in[5];
    const float* upd_w  = (const float*)d_in[6];
    const float* upd_b  = (const float*)d_in[7];
    const float* ecw    = (const float*)d_in[8];
    const float* ecb    = (const float*)d_in[9];
    float* out = (float*)d_out;

    // ---- workspace carve: ~205 MB ----
    char* p = (char*)d_ws;
    _Float16* Ahi = (_Float16*)p; p += (size_t)1048576*2;    //   2.0 MB
    _Float16* Alo = (_Float16*)p; p += (size_t)1048576*2;    //   2.0 MB
    short* WgQ  = (short*)p;  p += (size_t)33554432*2;       //  64.0 MB  [n][64][128][4] i16
    short* WuQ  = (short*)p;  p += (size_t)16777216*2;       //  32.0 MB  [n][64][64][4] i16
    float* swg  = (float*)p;  p += (size_t)131072*4;         //   0.5 MB
    float* swu  = (float*)p;  p += (size_t)65536*4;          //   0.25 MB
    float* bgn  = (float*)p;  p += (size_t)131072*4;         //   0.5 MB
    float* bun  = (float*)p;  p += (size_t)65536*4;          //   0.25 MB
    short* xqT  = (short*)p;  p += (size_t)25165824*2;       //  48.0 MB  [p][j][n] i16
    float* xscA = (float*)p;  p += (size_t)393216*4;         //   1.5 MB
    float* xscB = (float*)p;  p += (size_t)393216*4;         //   1.5 MB
    float* hbuf = (float*)p;  p += (size_t)1048576*4;        //   4.0 MB
    float* hT   = (float*)p;  p += (size_t)1048576*4;        //   4.0 MB
    float* zrb  = (float*)p;  p += (size_t)2097152*4;        //   8.0 MB
    float* zhT  = (float*)p;  p += (size_t)1048576*4;        //   4.0 MB
    float* pAh  = (float*)p;  p += (size_t)2097152*4;        //   8.0 MB  split-K pair
    float* pAx  = (float*)p;  p += (size_t)2097152*4;        //   8.0 MB  split-K pair
    float* pAzh = (float*)p;  p += (size_t)2097152*4;        //   8.0 MB  split-K pair
    float* gwT  = pAzh;   // 2 MB scratch, aliases pAzh (dead during layer setup)

    embedq4_k<<<dim3(16,24), 256, 0, stream>>>(source, vw, xqT, xscA);
    adj_k<<<1024, 256, 0, stream>>>(emb, Ahi, Alo);
    fill_k<<<1536, 256, 0, stream>>>(xscB, 1.f/32767.f, 393216);

    for (int l = 0; l < 2; ++l) {
        const float* xsc2 = (l == 0) ? xscA : xscB;
        wtrans_k<128><<<2048, 256, 0, stream>>>(gate_w + (size_t)l*524288, gwT);
        wnodeq2_k<128><<<dim3(256,4), 256, 0, stream>>>(emb, gwT, WgQ, swg);
        wtrans_k<64><<<1024, 256, 0, stream>>>(upd_w + (size_t)l*262144, gwT);
        wnodeq2_k<64><<<dim3(256,4), 256, 0, stream>>>(emb, gwT, WuQ, swu);
        bias_k<<<512, 256, 0, stream>>>(emb, gate_b + l*2048, bgn, 128);
        bias_k<<<256, 256, 0, stream>>>(emb, upd_b + l*1024, bun, 64);
        for (int ps = 0; ps < PWIN; ++ps) {
            short* xqT_p = xqT + ((size_t)ps << 20);
            const float* xsc_p = xsc2 + (size_t)ps*16384;
            if (ps == 0) {
                // h == 0: only A@x needed (job 1, both K-halves)
                gemm16_k<<<dim3(16,16,2), 256, 0, stream>>>(Ahi, Alo, hT, xqT_p, xsc_p, zhT, pAh, pAx, pAzh, 2);
                gate_k<1><<<1024, 256, 0, stream>>>(xqT_p, xsc_p, hbuf, pAx, pAh, WgQ, swg, bgn, zrb, zhT);
                if (l == 0)
                    upd_k<1,1><<<1024, 256, 0, stream>>>(xqT_p, xsc_p, hbuf, pAx, pAzh, zrb, WuQ, swu, bun, hT);
                else
                    upd_k<1,0><<<1024, 256, 0, stream>>>(xqT_p, xsc_p, hbuf, pAx, pAzh, zrb, WuQ, swu, bun, hT);
            } else {
                gemm16_k<<<dim3(16,16,4), 256, 0, stream>>>(Ahi, Alo, hT, xqT_p, xsc_p, zhT, pAh, pAx, pAzh, 0);
                gate_k<0><<<1024, 256, 0, stream>>>(xqT_p, xsc_p, hbuf, pAx, pAh, WgQ, swg, bgn, zrb, zhT);
                gemm16_k<<<dim3(16,16,2), 256, 0, stream>>>(Ahi, Alo, hT, xqT_p, xsc_p, zhT, pAh, pAx, pAzh, 4);
                if (l == 0)
                    upd_k<0,1><<<1024, 256, 0, stream>>>(xqT_p, xsc_p, hbuf, pAx, pAzh, zrb, WuQ, swu, bun, hT);
                else
                    upd_k<0,0><<<1024, 256, 0, stream>>>(xqT_p, xsc_p, hbuf, pAx, pAzh, zrb, WuQ, swu, bun, hT);
            }
        }
    }
    endconv_k<<<768, 256, 0, stream>>>(hbuf, ecw, ecb, out);
}

// Round 12
// 5013.872 us; speedup vs baseline: 2.8304x; 1.0405x over previous
//
#include <hip/hip_runtime.h>
#include <math.h>

#define N_NODES 1024
#define HID 64
#define BATCH 16
#define TSTEPS 288
#define PWIN 24
#define PL 12
#define EMB 16
#define HOR 12

typedef __attribute__((ext_vector_type(4))) short short4_t;
typedef __attribute__((ext_vector_type(8))) short short8_t;
typedef _Float16 f16x8 __attribute__((ext_vector_type(8)));
typedef _Float16 f16x4 __attribute__((ext_vector_type(4)));
typedef float f32x4 __attribute__((ext_vector_type(4)));

__global__ __launch_bounds__(256) void fill_k(float* p, float v, int n) {
    int i = blockIdx.x*256 + threadIdx.x;
    if (i < n) p[i] = v;
}

// block per (ngrp, p): lane = n (coalesced stores), wave wid covers b = 4*wid..+3.
// Two-pass per b (amax pass, quantize pass) with 8-wide register chunks.
__global__ __launch_bounds__(256) void embedq4_k(
    const float* __restrict__ src, const float* __restrict__ vw,
    short* __restrict__ xqT, float* __restrict__ xsc2)
{
    int p = blockIdx.y;
    int n0 = blockIdx.x * 64;
    int t = threadIdx.x;
    int lane = t & 63, wid = t >> 6;
    __shared__ float sv[192][64];     // [b*12+tt][n]
    __shared__ float wvs[PL*HID];
    __shared__ float pe[64];
    for (int r = wid; r < 192; r += 4) {
        int b = r / 12, tt = r - b*12;
        sv[r][lane] = src[((size_t)b*TSTEPS + p*PL + tt)*N_NODES + n0 + lane];
    }
    for (int i = t; i < PL*HID; i += 256) wvs[i] = vw[i];
    if (t < 64) {
        float d = expf(-(float)(t & ~1) * (float)(9.210340371976184/64.0));
        float arg = (float)p * d;
        pe[t] = (t & 1) ? cosf(arg) : sinf(arg);
    }
    __syncthreads();
#pragma unroll 1
    for (int bb = 0; bb < 4; ++bb) {
        int b = wid*4 + bb;
        float svr[12];
#pragma unroll
        for (int tt = 0; tt < 12; ++tt) svr[tt] = sv[b*12 + tt][lane];
        float amax = 0.f;
#pragma unroll 1
        for (int h0 = 0; h0 < 64; h0 += 8) {
#pragma unroll
            for (int hh = 0; hh < 8; ++hh) {
                int h = h0 + hh;
                float d = pe[h];
#pragma unroll
                for (int tt = 0; tt < 12; ++tt) d += svr[tt] * wvs[tt*HID + h];
                amax = fmaxf(amax, fabsf(d));
            }
        }
        float inv = (amax > 0.f) ? 32767.f/amax : 0.f;
        short* xp = xqT + ((size_t)p << 20) + (size_t)b*64*1024 + n0 + lane;
#pragma unroll 1
        for (int h0 = 0; h0 < 64; h0 += 8) {
#pragma unroll
            for (int hh = 0; hh < 8; ++hh) {
                int h = h0 + hh;
                float d = pe[h];
#pragma unroll
                for (int tt = 0; tt < 12; ++tt) d += svr[tt] * wvs[tt*HID + h];
                xp[(size_t)h*1024] = (short)__float2int_rn(d*inv);
            }
        }
        xsc2[((p*16 + b) << 10) + n0 + lane] = (amax > 0.f) ? amax/32767.f : 0.f;
    }
}

// A[n][m] = softmax_m(relu(emb[n]·emb[m])), written as plain f16.
// (Precision note: hi/lo compensated form is 3x MFMA cost; harness threshold
// is 4.875e-2 with bf16-floor at 7.8e-3 — plain f16 error ~1e-3/step fits.
// REVERT to R11's Ahi/Alo 3-MFMA form if absmax exceeds threshold.)
__global__ __launch_bounds__(256) void adj_k(const float* __restrict__ emb,
    _Float16* __restrict__ Ahi)
{
    __shared__ float en[EMB];
    __shared__ float red[256];
    int n = blockIdx.x, t = threadIdx.x;
    if (t < EMB) en[t] = emb[n*EMB + t];
    __syncthreads();
    float v[4]; float mx = 0.f;
#pragma unroll
    for (int q = 0; q < 4; ++q) {
        int m = q*256 + t;
        float dot = 0.f;
#pragma unroll
        for (int e = 0; e < EMB; ++e) dot += en[e]*emb[m*EMB + e];
        v[q] = fmaxf(dot, 0.f);
        mx = fmaxf(mx, v[q]);
    }
    red[t] = mx; __syncthreads();
    for (int s2 = 128; s2 > 0; s2 >>= 1) {
        if (t < s2) red[t] = fmaxf(red[t], red[t + s2]);
        __syncthreads();
    }
    mx = red[0]; __syncthreads();
    float sum = 0.f;
#pragma unroll
    for (int q = 0; q < 4; ++q) { v[q] = expf(v[q] - mx); sum += v[q]; }
    red[t] = sum; __syncthreads();
    for (int s2 = 128; s2 > 0; s2 >>= 1) {
        if (t < s2) red[t] += red[t + s2];
        __syncthreads();
    }
    float inv = 1.f / red[0];
#pragma unroll
    for (int q = 0; q < 4; ++q)
        Ahi[(size_t)n*N_NODES + q*256 + t] = (_Float16)(v[q]*inv);
}

// gwT[e][o][kc] <- gwl[e][kc][o]
template<int OUT>
__global__ __launch_bounds__(256) void wtrans_k(
    const float* __restrict__ gwl, float* __restrict__ gwT)
{
    int idx = blockIdx.x*256 + threadIdx.x;
    int kc = idx & 255;
    int rest = idx >> 8;
    int o = rest % OUT;
    int e = rest / OUT;
    gwT[idx] = gwl[((size_t)e*256 + kc)*OUT + o];
}

// W[n](o,kc) = sum_e emb[n][e]*gwT[e][o][kc], i16 with per-(n,o) row scale.
// Output layout [n][kc4][OUT][4] (4 consecutive k's per o) so the consumers'
// weight loads are lane-coalesced (o contiguous).
template<int OUT>
__global__ __launch_bounds__(256) void wnodeq2_k(
    const float* __restrict__ emb, const float* __restrict__ gwT,
    short* __restrict__ WQ, float* __restrict__ wsc)
{
    int t = threadIdx.x;
    int n0 = blockIdx.x * 4;
    int oh = blockIdx.y;
    int lane = t & 63, w = t >> 6;     // lane = kc quad index (kc = lane*4..+3)
    __shared__ float se[4][EMB];
    if (t < 4*EMB) se[t >> 4][t & 15] = emb[(n0 + (t >> 4))*EMB + (t & 15)];
    __syncthreads();
    for (int o = oh*(OUT/4) + w; o < (oh+1)*(OUT/4); o += 4) {
        const float* gp = gwT + (size_t)o*256 + lane*4;
        float4 s[4];
#pragma unroll
        for (int ng = 0; ng < 4; ++ng) s[ng] = make_float4(0.f, 0.f, 0.f, 0.f);
#pragma unroll
        for (int e = 0; e < EMB; ++e) {
            float4 g = *(const float4*)(gp + (size_t)e*(OUT*256));
#pragma unroll
            for (int ng = 0; ng < 4; ++ng) {
                float c = se[ng][e];
                s[ng].x += c*g.x; s[ng].y += c*g.y; s[ng].z += c*g.z; s[ng].w += c*g.w;
            }
        }
#pragma unroll
        for (int ng = 0; ng < 4; ++ng) {
            float amax = fmaxf(fmaxf(fabsf(s[ng].x), fabsf(s[ng].y)),
                               fmaxf(fabsf(s[ng].z), fabsf(s[ng].w)));
#pragma unroll
            for (int d = 32; d > 0; d >>= 1) amax = fmaxf(amax, __shfl_xor(amax, d));
            float inv = (amax > 0.f) ? 32767.f/amax : 0.f;
            short4_t q;
            q.x = (short)__float2int_rn(s[ng].x*inv);
            q.y = (short)__float2int_rn(s[ng].y*inv);
            q.z = (short)__float2int_rn(s[ng].z*inv);
            q.w = (short)__float2int_rn(s[ng].w*inv);
            // [n][kc4=lane][OUT][4]
            *(short4_t*)(WQ + (((size_t)(n0+ng)*64 + lane)*OUT + o)*4) = q;
            if (lane == 0) wsc[(n0+ng)*OUT + o] = (amax > 0.f) ? amax/32767.f : 0.f;
        }
    }
}

__global__ __launch_bounds__(256) void bias_k(const float* __restrict__ emb,
                        const float* __restrict__ gbl, float* __restrict__ bn, int OUT)
{
    int idx = blockIdx.x*256 + threadIdx.x;
    if (idx >= N_NODES*OUT) return;
    int n = idx / OUT, o = idx % OUT;
    float s = 0.f;
#pragma unroll
    for (int e = 0; e < EMB; ++e) s += emb[n*EMB + e]*gbl[e*OUT + o];
    bn[idx] = s;
}

// C = A@B via mfma_f32_16x16x32_f16, PLAIN f16 (A precomputed f16; B converted
// to f16 in staging; f32 accumulate). All jobs split-K=2 (ks halves written to
// out + ks*1M; consumers sum the pair). B operands TRANSPOSED [j][m]:
//   job 0: B = hT  f32              -> pAh
//   job 1: B = xqT i16 * xsc2[b][m] -> pAx
//   job 2: B = zhT f32              -> pAzh
// z = zoff + blockIdx.z in 0..5: job = z>>1, ks = z&1.
__global__ __launch_bounds__(256) void gemm16_k(
    const _Float16* __restrict__ Ahi,
    const float* __restrict__ hT, const short* __restrict__ xqTp,
    const float* __restrict__ xscp, const float* __restrict__ zhT,
    float* __restrict__ pAh, float* __restrict__ pAx, float* __restrict__ pAzh,
    int zoff)
{
    int z = zoff + blockIdx.z;
    int job = z >> 1, ks = z & 1;
    int kbase = ks << 9;
    float* out = ((job == 0) ? pAh : (job == 1) ? pAx : pAzh) + ((size_t)ks << 20);
    const float* BTf = (job == 0) ? hT : zhT;
    __shared__ _Float16 Ash[64*72];
    __shared__ _Float16 Bsh[64*72];
    int t = threadIdx.x;
    int l = t & 63, w = t >> 6;
    int wr = w >> 1, wc = w & 1;
    int r0 = blockIdx.y*64, c0 = blockIdx.x*64;
    f32x4 acc[2][2];
#pragma unroll
    for (int i = 0; i < 2; ++i)
#pragma unroll
        for (int j = 0; j < 2; ++j) acc[i][j] = (f32x4){0.f,0.f,0.f,0.f};
    int arow = wr*32 + (l & 15);
    int brow = wc*32 + (l & 15);
    int koff = (l >> 4)*8;
    const float* sbase = xscp + ((c0 >> 6) << 10);   // per-(b,n) x scales, b = c0/64
    for (int k0 = kbase; k0 < kbase + 512; k0 += 64) {
        __syncthreads();
        // A tile: coalesced f16x8 (512 loads, 2 per thread)
#pragma unroll
        for (int c = 0; c < 2; ++c) {
            int id = t + 256*c;
            int row = id >> 3, k8 = id & 7;
            *(f16x8*)(&Ash[row*72 + k8*8]) =
                *(const f16x8*)(&Ahi[(size_t)(r0+row)*1024 + k0 + k8*8]);
        }
        // B tile from transposed source, coalesced along m, f16 convert
        if (job == 1) {
#pragma unroll
            for (int c = 0; c < 2; ++c) {
                int id = t + 256*c;
                int row = id >> 3, k8 = id & 7;
                short8_t q8 = *(const short8_t*)(xqTp + (size_t)(c0+row)*1024 + k0 + k8*8);
                float4 s0 = *(const float4*)(sbase + k0 + k8*8);
                float4 s1 = *(const float4*)(sbase + k0 + k8*8 + 4);
                f16x8 hi;
                hi[0] = (_Float16)((float)q8[0]*s0.x); hi[1] = (_Float16)((float)q8[1]*s0.y);
                hi[2] = (_Float16)((float)q8[2]*s0.z); hi[3] = (_Float16)((float)q8[3]*s0.w);
                hi[4] = (_Float16)((float)q8[4]*s1.x); hi[5] = (_Float16)((float)q8[5]*s1.y);
                hi[6] = (_Float16)((float)q8[6]*s1.z); hi[7] = (_Float16)((float)q8[7]*s1.w);
                *(f16x8*)(&Bsh[row*72 + k8*8]) = hi;
            }
        } else {
#pragma unroll
            for (int c = 0; c < 4; ++c) {
                int id = t + 256*c;
                int row = id >> 4, kq = id & 15;
                float4 v = *(const float4*)(&BTf[(size_t)(c0+row)*1024 + k0 + kq*4]);
                f16x4 hi;
                hi[0] = (_Float16)v.x; hi[1] = (_Float16)v.y;
                hi[2] = (_Float16)v.z; hi[3] = (_Float16)v.w;
                *(f16x4*)(&Bsh[row*72 + kq*4]) = hi;
            }
        }
        __syncthreads();
#pragma unroll
        for (int kk = 0; kk < 2; ++kk) {
            int ko = kk*32 + koff;
            f16x8 ah0 = *(const f16x8*)(&Ash[(size_t)arow*72 + ko]);
            f16x8 ah1 = *(const f16x8*)(&Ash[(size_t)(arow+16)*72 + ko]);
            f16x8 bh0 = *(const f16x8*)(&Bsh[(size_t)brow*72 + ko]);
            f16x8 bh1 = *(const f16x8*)(&Bsh[(size_t)(brow+16)*72 + ko]);
            acc[0][0] = __builtin_amdgcn_mfma_f32_16x16x32_f16(ah0, bh0, acc[0][0], 0, 0, 0);
            acc[0][1] = __builtin_amdgcn_mfma_f32_16x16x32_f16(ah0, bh1, acc[0][1], 0, 0, 0);
            acc[1][0] = __builtin_amdgcn_mfma_f32_16x16x32_f16(ah1, bh0, acc[1][0], 0, 0, 0);
            acc[1][1] = __builtin_amdgcn_mfma_f32_16x16x32_f16(ah1, bh1, acc[1][1], 0, 0, 0);
        }
    }
    // C/D layout: col = lane&15, row = 4*(lane>>4)+reg  [measured m89/m91]
#pragma unroll
    for (int fr = 0; fr < 2; ++fr)
#pragma unroll
        for (int fc = 0; fc < 2; ++fc) {
            int orow = r0 + wr*32 + fr*16 + ((l >> 4) << 2);
            int ocol = c0 + wc*32 + fc*16 + (l & 15);
#pragma unroll
            for (int i = 0; i < 4; ++i)
                out[(size_t)(orow+i)*1024 + ocol] = acc[fr][fc][i];
        }
}

// zr[n][b][o] = sigmoid([x,h,Ax,Ah]·Wq[n](o,:)·ws + bg); writes zhT[j][n]=z*h.
// Weight loads coalesced via [n][kc4][128][4] layout (lane-consecutive o).
template<int FIRST>
__global__ __launch_bounds__(256) void gate_k(
    const short* __restrict__ xqTp, const float* __restrict__ xscp,
    const float* __restrict__ hst, const float* __restrict__ pAx,
    const float* __restrict__ pAh, const short* __restrict__ WQ,
    const float* __restrict__ wsc, const float* __restrict__ bg,
    float* __restrict__ zr, float* __restrict__ zhT)
{
    __shared__ float inp[16*256];
    int n = ((blockIdx.x & 7) << 7) | (blockIdx.x >> 3);
    int t = threadIdx.x;
    size_t nb = (size_t)n*1024;
    for (int i = t; i < 1024; i += 256) {
        int b = i >> 6, c = i & 63;
        float sx = xscp[(b << 10) + n];
        inp[b*256 + c]       = (float)xqTp[(size_t)i*1024 + n] * sx;
        inp[b*256 + 64 + c]  = FIRST ? 0.f : hst[nb + i];
        inp[b*256 + 128 + c] = pAx[nb + i] + pAx[nb + i + 1048576];
        inp[b*256 + 192 + c] = FIRST ? 0.f : (pAh[nb + i] + pAh[nb + i + 1048576]);
    }
    __syncthreads();
    int o = t & 127, g = t >> 7;
    const short* wp = WQ + (size_t)n*32768 + o*4;   // [n][kc4][128][4]
    float ws = wsc[n*128 + o];
    float bias = bg[n*128 + o];
    float acc[8];
#pragma unroll
    for (int u = 0; u < 8; ++u) acc[u] = 0.f;
    for (int k0 = 0; k0 < 256; k0 += 4) {
        short4_t w4 = *(const short4_t*)(wp + (size_t)(k0 >> 2)*512);
        float w0 = (float)w4.x, w1 = (float)w4.y, w2 = (float)w4.z, w3 = (float)w4.w;
#pragma unroll
        for (int u = 0; u < 8; ++u) {
            float4 iv = *(const float4*)(&inp[(g*8 + u)*256 + k0]);
            acc[u] += w0*iv.x + w1*iv.y + w2*iv.z + w3*iv.w;
        }
    }
#pragma unroll
    for (int u = 0; u < 8; ++u) {
        int b = g*8 + u;
        float pre = acc[u]*ws + bias;
        float val = 1.f/(1.f + expf(-pre));
        zr[((size_t)n*16 + b)*128 + o] = val;
        if (!FIRST && o < 64)
            zhT[(size_t)(b*64 + o)*1024 + n] = val * inp[b*256 + 64 + o];
    }
}

// h_new = r*h + (1-r)*tanh([x, z*h, Ax, Azh]·Wu[n]·ws + bu); writes hst rows,
// hT columns, (WX) next-layer xqT i16 columns. Coalesced weights [n][kc4][64][4].
template<int FIRST, int WX>
__global__ __launch_bounds__(256) void upd_k(
    short* __restrict__ xqTp, const float* __restrict__ xscp,
    float* __restrict__ hst, const float* __restrict__ pAx,
    const float* __restrict__ pAzh, const float* __restrict__ zr,
    const short* __restrict__ WQ, const float* __restrict__ wsc,
    const float* __restrict__ bu, float* __restrict__ hT)
{
    __shared__ float inp[16*256];
    int n = ((blockIdx.x & 7) << 7) | (blockIdx.x >> 3);
    int t = threadIdx.x;
    size_t nb = (size_t)n*1024;
    for (int i = t; i < 1024; i += 256) {
        int b = i >> 6, c = i & 63;
        float sx = xscp[(b << 10) + n];
        float hv = FIRST ? 0.f : hst[nb + i];
        float zv = zr[((size_t)n*16 + b)*128 + c];
        inp[b*256 + c]       = (float)xqTp[(size_t)i*1024 + n] * sx;
        inp[b*256 + 64 + c]  = zv * hv;
        inp[b*256 + 128 + c] = pAx[nb + i] + pAx[nb + i + 1048576];
        inp[b*256 + 192 + c] = FIRST ? 0.f : (pAzh[nb + i] + pAzh[nb + i + 1048576]);
    }
    __syncthreads();
    int o = t & 63, g = t >> 6;
    const short* wp = WQ + (size_t)n*16384 + o*4;   // [n][kc4][64][4]
    float ws = wsc[n*64 + o];
    float bias = bu[n*64 + o];
    float acc[4];
#pragma unroll
    for (int u = 0; u < 4; ++u) acc[u] = 0.f;
    for (int k0 = 0; k0 < 256; k0 += 4) {
        short4_t w4 = *(const short4_t*)(wp + (size_t)(k0 >> 2)*256);
        float w0 = (float)w4.x, w1 = (float)w4.y, w2 = (float)w4.z, w3 = (float)w4.w;
#pragma unroll
        for (int u = 0; u < 4; ++u) {
            float4 iv = *(const float4*)(&inp[(g*4 + u)*256 + k0]);
            acc[u] += w0*iv.x + w1*iv.y + w2*iv.z + w3*iv.w;
        }
    }
#pragma unroll
    for (int u = 0; u < 4; ++u) {
        int b = g*4 + u;
        float r = zr[((size_t)n*16 + b)*128 + 64 + o];
        float hold = FIRST ? 0.f : hst[nb + b*64 + o];
        float hc = tanhf(acc[u]*ws + bias);
        float hn = r*hold + (1.f - r)*hc;
        hst[nb + b*64 + o] = hn;
        hT[(size_t)(b*64 + o)*1024 + n] = hn;
        if (WX) xqTp[(size_t)(b*64 + o)*1024 + n] = (short)__float2int_rn(hn*32767.f);
    }
}

// out[b][o][n] = h[n][b][:]·ecw[o][:] + ecb[o]
__global__ __launch_bounds__(256) void endconv_k(
    const float* __restrict__ hst, const float* __restrict__ ecw,
    const float* __restrict__ ecb, float* __restrict__ out)
{
    int idx = blockIdx.x*256 + threadIdx.x;
    int n = idx & 1023;
    int o = (idx >> 10) % HOR;
    int b = idx / (HOR*1024);
    float s = ecb[o];
#pragma unroll
    for (int hh = 0; hh < 64; ++hh)
        s += hst[((size_t)n*16 + b)*64 + hh] * ecw[o*64 + hh];
    out[idx] = s;
}

extern "C" void kernel_launch(void* const* d_in, const int* in_sizes, int n_in,
                              void* d_out, int out_size, void* d_ws, size_t ws_size,
                              hipStream_t stream)
{
    const float* source = (const float*)d_in[0];
    const float* emb    = (const float*)d_in[2];
    const float* vw     = (const float*)d_in[3];
    const float* gate_w = (const float*)d_in[4];
    const float* gate_b = (const float*)d_in[5];
    const float* upd_w  = (const float*)d_in[6];
    const float* upd_b  = (const float*)d_in[7];
    const float* ecw    = (const float*)d_in[8];
    const float* ecb    = (const float*)d_in[9];
    float* out = (float*)d_out;

    // ---- workspace carve: ~203 MB ----
    char* p = (char*)d_ws;
    _Float16* Ahi = (_Float16*)p; p += (size_t)1048576*2;    //   2.0 MB
    short* WgQ  = (short*)p;  p += (size_t)33554432*2;       //  64.0 MB  [n][64][128][4] i16
    short* WuQ  = (short*)p;  p += (size_t)16777216*2;       //  32.0 MB  [n][64][64][4] i16
    float* swg  = (float*)p;  p += (size_t)131072*4;         //   0.5 MB
    float* swu  = (float*)p;  p += (size_t)65536*4;          //   0.25 MB
    float* bgn  = (float*)p;  p += (size_t)131072*4;         //   0.5 MB
    float* bun  = (float*)p;  p += (size_t)65536*4;          //   0.25 MB
    short* xqT  = (short*)p;  p += (size_t)25165824*2;       //  48.0 MB  [p][j][n] i16
    float* xscA = (float*)p;  p += (size_t)393216*4;         //   1.5 MB
    float* xscB = (float*)p;  p += (size_t)393216*4;         //   1.5 MB
    float* hbuf = (float*)p;  p += (size_t)1048576*4;        //   4.0 MB
    float* hT   = (float*)p;  p += (size_t)1048576*4;        //   4.0 MB
    float* zrb  = (float*)p;  p += (size_t)2097152*4;        //   8.0 MB
    float* zhT  = (float*)p;  p += (size_t)1048576*4;        //   4.0 MB
    float* pAh  = (float*)p;  p += (size_t)2097152*4;        //   8.0 MB  split-K pair
    float* pAx  = (float*)p;  p += (size_t)2097152*4;        //   8.0 MB  split-K pair
    float* pAzh = (float*)p;  p += (size_t)2097152*4;        //   8.0 MB  split-K pair
    float* gwT  = pAzh;   // 2 MB scratch, aliases pAzh (dead during layer setup)

    embedq4_k<<<dim3(16,24), 256, 0, stream>>>(source, vw, xqT, xscA);
    adj_k<<<1024, 256, 0, stream>>>(emb, Ahi);
    fill_k<<<1536, 256, 0, stream>>>(xscB, 1.f/32767.f, 393216);

    for (int l = 0; l < 2; ++l) {
        const float* xsc2 = (l == 0) ? xscA : xscB;
        wtrans_k<128><<<2048, 256, 0, stream>>>(gate_w + (size_t)l*524288, gwT);
        wnodeq2_k<128><<<dim3(256,4), 256, 0, stream>>>(emb, gwT, WgQ, swg);
        wtrans_k<64><<<1024, 256, 0, stream>>>(upd_w + (size_t)l*262144, gwT);
        wnodeq2_k<64><<<dim3(256,4), 256, 0, stream>>>(emb, gwT, WuQ, swu);
        bias_k<<<512, 256, 0, stream>>>(emb, gate_b + l*2048, bgn, 128);
        bias_k<<<256, 256, 0, stream>>>(emb, upd_b + l*1024, bun, 64);
        for (int ps = 0; ps < PWIN; ++ps) {
            short* xqT_p = xqT + ((size_t)ps << 20);
            const float* xsc_p = xsc2 + (size_t)ps*16384;
            if (ps == 0) {
                // h == 0: only A@x needed (job 1, both K-halves)
                gemm16_k<<<dim3(16,16,2), 256, 0, stream>>>(Ahi, hT, xqT_p, xsc_p, zhT, pAh, pAx, pAzh, 2);
                gate_k<1><<<1024, 256, 0, stream>>>(xqT_p, xsc_p, hbuf, pAx, pAh, WgQ, swg, bgn, zrb, zhT);
                if (l == 0)
                    upd_k<1,1><<<1024, 256, 0, stream>>>(xqT_p, xsc_p, hbuf, pAx, pAzh, zrb, WuQ, swu, bun, hT);
                else
                    upd_k<1,0><<<1024, 256, 0, stream>>>(xqT_p, xsc_p, hbuf, pAx, pAzh, zrb, WuQ, swu, bun, hT);
            } else {
                gemm16_k<<<dim3(16,16,4), 256, 0, stream>>>(Ahi, hT, xqT_p, xsc_p, zhT, pAh, pAx, pAzh, 0);
                gate_k<0><<<1024, 256, 0, stream>>>(xqT_p, xsc_p, hbuf, pAx, pAh, WgQ, swg, bgn, zrb, zhT);
                gemm16_k<<<dim3(16,16,2), 256, 0, stream>>>(Ahi, hT, xqT_p, xsc_p, zhT, pAh, pAx, pAzh, 4);
                if (l == 0)
                    upd_k<0,1><<<1024, 256, 0, stream>>>(xqT_p, xsc_p, hbuf, pAx, pAzh, zrb, WuQ, swu, bun, hT);
                else
                    upd_k<0,0><<<1024, 256, 0, stream>>>(xqT_p, xsc_p, hbuf, pAx, pAzh, zrb, WuQ, swu, bun, hT);
            }
        }
    }
    endconv_k<<<768, 256, 0, stream>>>(hbuf, ecw, ecb, out);
}

// Round 13
// 4407.972 us; speedup vs baseline: 3.2194x; 1.1375x over previous
//
#include <hip/hip_runtime.h>
#include <math.h>

#define N_NODES 1024
#define HID 64
#define BATCH 16
#define TSTEPS 288
#define PWIN 24
#define PL 12
#define EMB 16
#define HOR 12

typedef __attribute__((ext_vector_type(4))) short short4_t;
typedef __attribute__((ext_vector_type(8))) short short8_t;
typedef _Float16 f16x8 __attribute__((ext_vector_type(8)));
typedef _Float16 f16x4 __attribute__((ext_vector_type(4)));
typedef float f32x4 __attribute__((ext_vector_type(4)));

// block per (ngrp, p): lane = n (coalesced 128B stores), wave wid covers b = 4*wid..+3.
// Single pass (f16 output, no amax/scale): x[p][j=b*64+h][n] f16.
__global__ __launch_bounds__(256) void embedq5_k(
    const float* __restrict__ src, const float* __restrict__ vw,
    _Float16* __restrict__ xqT)
{
    int p = blockIdx.y;
    int n0 = blockIdx.x * 64;
    int t = threadIdx.x;
    int lane = t & 63, wid = t >> 6;
    __shared__ float sv[192][64];     // [b*12+tt][n]
    __shared__ float wvs[PL*HID];
    __shared__ float pe[64];
    for (int r = wid; r < 192; r += 4) {
        int b = r / 12, tt = r - b*12;
        sv[r][lane] = src[((size_t)b*TSTEPS + p*PL + tt)*N_NODES + n0 + lane];
    }
    for (int i = t; i < PL*HID; i += 256) wvs[i] = vw[i];
    if (t < 64) {
        float d = expf(-(float)(t & ~1) * (float)(9.210340371976184/64.0));
        float arg = (float)p * d;
        pe[t] = (t & 1) ? cosf(arg) : sinf(arg);
    }
    __syncthreads();
#pragma unroll 1
    for (int bb = 0; bb < 4; ++bb) {
        int b = wid*4 + bb;
        float svr[12];
#pragma unroll
        for (int tt = 0; tt < 12; ++tt) svr[tt] = sv[b*12 + tt][lane];
        _Float16* xp = xqT + ((size_t)p << 20) + (size_t)b*64*1024 + n0 + lane;
#pragma unroll 1
        for (int h0 = 0; h0 < 64; h0 += 8) {
#pragma unroll
            for (int hh = 0; hh < 8; ++hh) {
                int h = h0 + hh;
                float d = pe[h];
#pragma unroll
                for (int tt = 0; tt < 12; ++tt) d += svr[tt] * wvs[tt*HID + h];
                xp[(size_t)h*1024] = (_Float16)d;
            }
        }
    }
}

// A[n][m] = softmax_m(relu(emb[n]·emb[m])), written as plain f16.
__global__ __launch_bounds__(256) void adj_k(const float* __restrict__ emb,
    _Float16* __restrict__ Ahi)
{
    __shared__ float en[EMB];
    __shared__ float red[256];
    int n = blockIdx.x, t = threadIdx.x;
    if (t < EMB) en[t] = emb[n*EMB + t];
    __syncthreads();
    float v[4]; float mx = 0.f;
#pragma unroll
    for (int q = 0; q < 4; ++q) {
        int m = q*256 + t;
        float dot = 0.f;
#pragma unroll
        for (int e = 0; e < EMB; ++e) dot += en[e]*emb[m*EMB + e];
        v[q] = fmaxf(dot, 0.f);
        mx = fmaxf(mx, v[q]);
    }
    red[t] = mx; __syncthreads();
    for (int s2 = 128; s2 > 0; s2 >>= 1) {
        if (t < s2) red[t] = fmaxf(red[t], red[t + s2]);
        __syncthreads();
    }
    mx = red[0]; __syncthreads();
    float sum = 0.f;
#pragma unroll
    for (int q = 0; q < 4; ++q) { v[q] = expf(v[q] - mx); sum += v[q]; }
    red[t] = sum; __syncthreads();
    for (int s2 = 128; s2 > 0; s2 >>= 1) {
        if (t < s2) red[t] += red[t + s2];
        __syncthreads();
    }
    float inv = 1.f / red[0];
#pragma unroll
    for (int q = 0; q < 4; ++q)
        Ahi[(size_t)n*N_NODES + q*256 + t] = (_Float16)(v[q]*inv);
}

// gwT[e][o][kc] <- gwl[e][kc][o]
template<int OUT>
__global__ __launch_bounds__(256) void wtrans_k(
    const float* __restrict__ gwl, float* __restrict__ gwT)
{
    int idx = blockIdx.x*256 + threadIdx.x;
    int kc = idx & 255;
    int rest = idx >> 8;
    int o = rest % OUT;
    int e = rest / OUT;
    gwT[idx] = gwl[((size_t)e*256 + kc)*OUT + o];
}

// W[n](o,kc) = sum_e emb[n][e]*gwT[e][o][kc], i16 with per-(n,o) row scale.
// Output layout [n][kc4][OUT][4] so consumers' weight loads are lane-coalesced.
template<int OUT>
__global__ __launch_bounds__(256) void wnodeq2_k(
    const float* __restrict__ emb, const float* __restrict__ gwT,
    short* __restrict__ WQ, float* __restrict__ wsc)
{
    int t = threadIdx.x;
    int n0 = blockIdx.x * 4;
    int oh = blockIdx.y;
    int lane = t & 63, w = t >> 6;     // lane = kc quad index (kc = lane*4..+3)
    __shared__ float se[4][EMB];
    if (t < 4*EMB) se[t >> 4][t & 15] = emb[(n0 + (t >> 4))*EMB + (t & 15)];
    __syncthreads();
    for (int o = oh*(OUT/4) + w; o < (oh+1)*(OUT/4); o += 4) {
        const float* gp = gwT + (size_t)o*256 + lane*4;
        float4 s[4];
#pragma unroll
        for (int ng = 0; ng < 4; ++ng) s[ng] = make_float4(0.f, 0.f, 0.f, 0.f);
#pragma unroll
        for (int e = 0; e < EMB; ++e) {
            float4 g = *(const float4*)(gp + (size_t)e*(OUT*256));
#pragma unroll
            for (int ng = 0; ng < 4; ++ng) {
                float c = se[ng][e];
                s[ng].x += c*g.x; s[ng].y += c*g.y; s[ng].z += c*g.z; s[ng].w += c*g.w;
            }
        }
#pragma unroll
        for (int ng = 0; ng < 4; ++ng) {
            float amax = fmaxf(fmaxf(fabsf(s[ng].x), fabsf(s[ng].y)),
                               fmaxf(fabsf(s[ng].z), fabsf(s[ng].w)));
#pragma unroll
            for (int d = 32; d > 0; d >>= 1) amax = fmaxf(amax, __shfl_xor(amax, d));
            float inv = (amax > 0.f) ? 32767.f/amax : 0.f;
            short4_t q;
            q.x = (short)__float2int_rn(s[ng].x*inv);
            q.y = (short)__float2int_rn(s[ng].y*inv);
            q.z = (short)__float2int_rn(s[ng].z*inv);
            q.w = (short)__float2int_rn(s[ng].w*inv);
            // [n][kc4=lane][OUT][4]
            *(short4_t*)(WQ + (((size_t)(n0+ng)*64 + lane)*OUT + o)*4) = q;
            if (lane == 0) wsc[(n0+ng)*OUT + o] = (amax > 0.f) ? amax/32767.f : 0.f;
        }
    }
}

__global__ __launch_bounds__(256) void bias_k(const float* __restrict__ emb,
                        const float* __restrict__ gbl, float* __restrict__ bn, int OUT)
{
    int idx = blockIdx.x*256 + threadIdx.x;
    if (idx >= N_NODES*OUT) return;
    int n = idx / OUT, o = idx % OUT;
    float s = 0.f;
#pragma unroll
    for (int e = 0; e < EMB; ++e) s += emb[n*EMB + e]*gbl[e*OUT + o];
    bn[idx] = s;
}

// C = A@B via mfma_f32_16x16x32_f16, plain f16, f32 accumulate. All operands
// f16 in memory; B TRANSPOSED [j][m] so staging is a straight f16x8 copy.
//   job 0: B = hT16  -> pAh;  job 1: B = xqT16 -> pAx;  job 2: B = zhT16 -> pAzh
// All jobs split-K=2 (ks halves to out + ks*1M; consumers sum the pair).
// z = zoff + blockIdx.z in 0..5: job = z>>1, ks = z&1.
__global__ __launch_bounds__(256) void gemm16_k(
    const _Float16* __restrict__ Ahi,
    const _Float16* __restrict__ hT16, const _Float16* __restrict__ xqT16p,
    const _Float16* __restrict__ zhT16,
    float* __restrict__ pAh, float* __restrict__ pAx, float* __restrict__ pAzh,
    int zoff)
{
    int z = zoff + blockIdx.z;
    int job = z >> 1, ks = z & 1;
    int kbase = ks << 9;
    float* out = ((job == 0) ? pAh : (job == 1) ? pAx : pAzh) + ((size_t)ks << 20);
    const _Float16* BT16 = (job == 0) ? hT16 : ((job == 1) ? xqT16p : zhT16);
    __shared__ _Float16 Ash[64*72];
    __shared__ _Float16 Bsh[64*72];
    int t = threadIdx.x;
    int l = t & 63, w = t >> 6;
    int wr = w >> 1, wc = w & 1;
    int r0 = blockIdx.y*64, c0 = blockIdx.x*64;
    f32x4 acc[2][2];
#pragma unroll
    for (int i = 0; i < 2; ++i)
#pragma unroll
        for (int j = 0; j < 2; ++j) acc[i][j] = (f32x4){0.f,0.f,0.f,0.f};
    int arow = wr*32 + (l & 15);
    int brow = wc*32 + (l & 15);
    int koff = (l >> 4)*8;
    for (int k0 = kbase; k0 < kbase + 512; k0 += 64) {
        __syncthreads();
#pragma unroll
        for (int c = 0; c < 2; ++c) {
            int id = t + 256*c;
            int row = id >> 3, k8 = id & 7;
            *(f16x8*)(&Ash[row*72 + k8*8]) =
                *(const f16x8*)(&Ahi[(size_t)(r0+row)*1024 + k0 + k8*8]);
            *(f16x8*)(&Bsh[row*72 + k8*8]) =
                *(const f16x8*)(&BT16[(size_t)(c0+row)*1024 + k0 + k8*8]);
        }
        __syncthreads();
#pragma unroll
        for (int kk = 0; kk < 2; ++kk) {
            int ko = kk*32 + koff;
            f16x8 ah0 = *(const f16x8*)(&Ash[(size_t)arow*72 + ko]);
            f16x8 ah1 = *(const f16x8*)(&Ash[(size_t)(arow+16)*72 + ko]);
            f16x8 bh0 = *(const f16x8*)(&Bsh[(size_t)brow*72 + ko]);
            f16x8 bh1 = *(const f16x8*)(&Bsh[(size_t)(brow+16)*72 + ko]);
            acc[0][0] = __builtin_amdgcn_mfma_f32_16x16x32_f16(ah0, bh0, acc[0][0], 0, 0, 0);
            acc[0][1] = __builtin_amdgcn_mfma_f32_16x16x32_f16(ah0, bh1, acc[0][1], 0, 0, 0);
            acc[1][0] = __builtin_amdgcn_mfma_f32_16x16x32_f16(ah1, bh0, acc[1][0], 0, 0, 0);
            acc[1][1] = __builtin_amdgcn_mfma_f32_16x16x32_f16(ah1, bh1, acc[1][1], 0, 0, 0);
        }
    }
    // C/D layout: col = lane&15, row = 4*(lane>>4)+reg  [measured m89/m91]
#pragma unroll
    for (int fr = 0; fr < 2; ++fr)
#pragma unroll
        for (int fc = 0; fc < 2; ++fc) {
            int orow = r0 + wr*32 + fr*16 + ((l >> 4) << 2);
            int ocol = c0 + wc*32 + fc*16 + (l & 15);
#pragma unroll
            for (int i = 0; i < 4; ++i)
                out[(size_t)(orow+i)*1024 + ocol] = acc[fr][fc][i];
        }
}

// zr[n][b][o] = sigmoid([x,h,Ax,Ah]·Wq[n](o,:)·ws + bg); writes zhT16[j][n]=z*h.
// Weight loads coalesced via [n][kc4][128][4] layout.
template<int FIRST>
__global__ __launch_bounds__(256) void gate_k(
    const _Float16* __restrict__ xqT16p,
    const float* __restrict__ hst, const float* __restrict__ pAx,
    const float* __restrict__ pAh, const short* __restrict__ WQ,
    const float* __restrict__ wsc, const float* __restrict__ bg,
    float* __restrict__ zr, _Float16* __restrict__ zhT16)
{
    __shared__ float inp[16*256];
    int n = ((blockIdx.x & 7) << 7) | (blockIdx.x >> 3);
    int t = threadIdx.x;
    size_t nb = (size_t)n*1024;
    for (int i = t; i < 1024; i += 256) {
        int b = i >> 6, c = i & 63;
        inp[b*256 + c]       = (float)xqT16p[(size_t)i*1024 + n];
        inp[b*256 + 64 + c]  = FIRST ? 0.f : hst[nb + i];
        inp[b*256 + 128 + c] = pAx[nb + i] + pAx[nb + i + 1048576];
        inp[b*256 + 192 + c] = FIRST ? 0.f : (pAh[nb + i] + pAh[nb + i + 1048576]);
    }
    __syncthreads();
    int o = t & 127, g = t >> 7;
    const short* wp = WQ + (size_t)n*32768 + o*4;   // [n][kc4][128][4]
    float ws = wsc[n*128 + o];
    float bias = bg[n*128 + o];
    float acc[8];
#pragma unroll
    for (int u = 0; u < 8; ++u) acc[u] = 0.f;
    for (int k0 = 0; k0 < 256; k0 += 4) {
        short4_t w4 = *(const short4_t*)(wp + (size_t)(k0 >> 2)*512);
        float w0 = (float)w4.x, w1 = (float)w4.y, w2 = (float)w4.z, w3 = (float)w4.w;
#pragma unroll
        for (int u = 0; u < 8; ++u) {
            float4 iv = *(const float4*)(&inp[(g*8 + u)*256 + k0]);
            acc[u] += w0*iv.x + w1*iv.y + w2*iv.z + w3*iv.w;
        }
    }
#pragma unroll
    for (int u = 0; u < 8; ++u) {
        int b = g*8 + u;
        float pre = acc[u]*ws + bias;
        float val = 1.f/(1.f + expf(-pre));
        zr[((size_t)n*16 + b)*128 + o] = val;
        if (!FIRST && o < 64)
            zhT16[(size_t)(b*64 + o)*1024 + n] = (_Float16)(val * inp[b*256 + 64 + o]);
    }
}

// h_new = r*h + (1-r)*tanh([x, z*h, Ax, Azh]·Wu[n]·ws + bu); writes hst rows (f32),
// hT16 columns (f16), (WX) next-layer xqT16 columns (f16). Coalesced weights.
template<int FIRST, int WX>
__global__ __launch_bounds__(256) void upd_k(
    _Float16* __restrict__ xqT16p,
    float* __restrict__ hst, const float* __restrict__ pAx,
    const float* __restrict__ pAzh, const float* __restrict__ zr,
    const short* __restrict__ WQ, const float* __restrict__ wsc,
    const float* __restrict__ bu, _Float16* __restrict__ hT16)
{
    __shared__ float inp[16*256];
    int n = ((blockIdx.x & 7) << 7) | (blockIdx.x >> 3);
    int t = threadIdx.x;
    size_t nb = (size_t)n*1024;
    for (int i = t; i < 1024; i += 256) {
        int b = i >> 6, c = i & 63;
        float hv = FIRST ? 0.f : hst[nb + i];
        float zv = zr[((size_t)n*16 + b)*128 + c];
        inp[b*256 + c]       = (float)xqT16p[(size_t)i*1024 + n];
        inp[b*256 + 64 + c]  = zv * hv;
        inp[b*256 + 128 + c] = pAx[nb + i] + pAx[nb + i + 1048576];
        inp[b*256 + 192 + c] = FIRST ? 0.f : (pAzh[nb + i] + pAzh[nb + i + 1048576]);
    }
    __syncthreads();
    int o = t & 63, g = t >> 6;
    const short* wp = WQ + (size_t)n*16384 + o*4;   // [n][kc4][64][4]
    float ws = wsc[n*64 + o];
    float bias = bu[n*64 + o];
    float acc[4];
#pragma unroll
    for (int u = 0; u < 4; ++u) acc[u] = 0.f;
    for (int k0 = 0; k0 < 256; k0 += 4) {
        short4_t w4 = *(const short4_t*)(wp + (size_t)(k0 >> 2)*256);
        float w0 = (float)w4.x, w1 = (float)w4.y, w2 = (float)w4.z, w3 = (float)w4.w;
#pragma unroll
        for (int u = 0; u < 4; ++u) {
            float4 iv = *(const float4*)(&inp[(g*4 + u)*256 + k0]);
            acc[u] += w0*iv.x + w1*iv.y + w2*iv.z + w3*iv.w;
        }
    }
#pragma unroll
    for (int u = 0; u < 4; ++u) {
        int b = g*4 + u;
        float r = zr[((size_t)n*16 + b)*128 + 64 + o];
        float hold = FIRST ? 0.f : hst[nb + b*64 + o];
        float hc = tanhf(acc[u]*ws + bias);
        float hn = r*hold + (1.f - r)*hc;
        hst[nb + b*64 + o] = hn;
        hT16[(size_t)(b*64 + o)*1024 + n] = (_Float16)hn;
        if (WX) xqT16p[(size_t)(b*64 + o)*1024 + n] = (_Float16)hn;
    }
}

// out[b][o][n] = h[n][b][:]·ecw[o][:] + ecb[o]
__global__ __launch_bounds__(256) void endconv_k(
    const float* __restrict__ hst, const float* __restrict__ ecw,
    const float* __restrict__ ecb, float* __restrict__ out)
{
    int idx = blockIdx.x*256 + threadIdx.x;
    int n = idx & 1023;
    int o = (idx >> 10) % HOR;
    int b = idx / (HOR*1024);
    float s = ecb[o];
#pragma unroll
    for (int hh = 0; hh < 64; ++hh)
        s += hst[((size_t)n*16 + b)*64 + hh] * ecw[o*64 + hh];
    out[idx] = s;
}

extern "C" void kernel_launch(void* const* d_in, const int* in_sizes, int n_in,
                              void* d_out, int out_size, void* d_ws, size_t ws_size,
                              hipStream_t stream)
{
    const float* source = (const float*)d_in[0];
    const float* emb    = (const float*)d_in[2];
    const float* vw     = (const float*)d_in[3];
    const float* gate_w = (const float*)d_in[4];
    const float* gate_b = (const float*)d_in[5];
    const float* upd_w  = (const float*)d_in[6];
    const float* upd_b  = (const float*)d_in[7];
    const float* ecw    = (const float*)d_in[8];
    const float* ecb    = (const float*)d_in[9];
    float* out = (float*)d_out;

    // ---- workspace carve: ~199 MB ----
    char* p = (char*)d_ws;
    _Float16* Ahi = (_Float16*)p; p += (size_t)1048576*2;    //   2.0 MB
    short* WgQ  = (short*)p;  p += (size_t)33554432*2;       //  64.0 MB  [n][64][128][4] i16
    short* WuQ  = (short*)p;  p += (size_t)16777216*2;       //  32.0 MB  [n][64][64][4] i16
    float* swg  = (float*)p;  p += (size_t)131072*4;         //   0.5 MB
    float* swu  = (float*)p;  p += (size_t)65536*4;          //   0.25 MB
    float* bgn  = (float*)p;  p += (size_t)131072*4;         //   0.5 MB
    float* bun  = (float*)p;  p += (size_t)65536*4;          //   0.25 MB
    _Float16* xqT = (_Float16*)p; p += (size_t)25165824*2;   //  48.0 MB  [p][j][n] f16
    float* hbuf = (float*)p;  p += (size_t)1048576*4;        //   4.0 MB  h rows f32
    _Float16* hT16 = (_Float16*)p; p += (size_t)1048576*2;   //   2.0 MB  h cols f16
    float* zrb  = (float*)p;  p += (size_t)2097152*4;        //   8.0 MB
    _Float16* zhT16 = (_Float16*)p; p += (size_t)1048576*2;  //   2.0 MB  (z*h)^T f16
    float* pAh  = (float*)p;  p += (size_t)2097152*4;        //   8.0 MB  split-K pair
    float* pAx  = (float*)p;  p += (size_t)2097152*4;        //   8.0 MB  split-K pair
    float* pAzh = (float*)p;  p += (size_t)2097152*4;        //   8.0 MB  split-K pair
    float* gwT  = pAzh;   // 2 MB scratch, aliases pAzh (dead during layer setup)

    embedq5_k<<<dim3(16,24), 256, 0, stream>>>(source, vw, xqT);
    adj_k<<<1024, 256, 0, stream>>>(emb, Ahi);

    for (int l = 0; l < 2; ++l) {
        wtrans_k<128><<<2048, 256, 0, stream>>>(gate_w + (size_t)l*524288, gwT);
        wnodeq2_k<128><<<dim3(256,4), 256, 0, stream>>>(emb, gwT, WgQ, swg);
        wtrans_k<64><<<1024, 256, 0, stream>>>(upd_w + (size_t)l*262144, gwT);
        wnodeq2_k<64><<<dim3(256,4), 256, 0, stream>>>(emb, gwT, WuQ, swu);
        bias_k<<<512, 256, 0, stream>>>(emb, gate_b + l*2048, bgn, 128);
        bias_k<<<256, 256, 0, stream>>>(emb, upd_b + l*1024, bun, 64);
        for (int ps = 0; ps < PWIN; ++ps) {
            _Float16* xqT_p = xqT + ((size_t)ps << 20);
            if (ps == 0) {
                // h == 0: only A@x needed (job 1, both K-halves)
                gemm16_k<<<dim3(16,16,2), 256, 0, stream>>>(Ahi, hT16, xqT_p, zhT16, pAh, pAx, pAzh, 2);
                gate_k<1><<<1024, 256, 0, stream>>>(xqT_p, hbuf, pAx, pAh, WgQ, swg, bgn, zrb, zhT16);
                if (l == 0)
                    upd_k<1,1><<<1024, 256, 0, stream>>>(xqT_p, hbuf, pAx, pAzh, zrb, WuQ, swu, bun, hT16);
                else
                    upd_k<1,0><<<1024, 256, 0, stream>>>(xqT_p, hbuf, pAx, pAzh, zrb, WuQ, swu, bun, hT16);
            } else {
                gemm16_k<<<dim3(16,16,4), 256, 0, stream>>>(Ahi, hT16, xqT_p, zhT16, pAh, pAx, pAzh, 0);
                gate_k<0><<<1024, 256, 0, stream>>>(xqT_p, hbuf, pAx, pAh, WgQ, swg, bgn, zrb, zhT16);
                gemm16_k<<<dim3(16,16,2), 256, 0, stream>>>(Ahi, hT16, xqT_p, zhT16, pAh, pAx, pAzh, 4);
                if (l == 0)
                    upd_k<0,1><<<1024, 256, 0, stream>>>(xqT_p, hbuf, pAx, pAzh, zrb, WuQ, swu, bun, hT16);
                else
                    upd_k<0,0><<<1024, 256, 0, stream>>>(xqT_p, hbuf, pAx, pAzh, zrb, WuQ, swu, bun, hT16);
            }
        }
    }
    endconv_k<<<768, 256, 0, stream>>>(hbuf, ecw, ecb, out);
}